// Round 3
// baseline (935.713 us; speedup 1.0000x reference)
//
#include <hip/hip_runtime.h>
#include <math.h>

#define B_ 2
#define S_ 1024
#define D_ 128
#define N_ 256
#define L_ 2
#define H_ 2
#define V_ 32000

#define INV2PI 0.15915494309189535f
#define PHI_F 1.61803398874989484f

__device__ __forceinline__ float fract_(float x) { return x - floorf(x); }
// v_sin/v_cos take revolutions; reduce first.
__device__ __forceinline__ float fsin_(float th) { return __builtin_amdgcn_sinf(fract_(th * INV2PI)); }
__device__ __forceinline__ float fcos_(float th) { return __builtin_amdgcn_cosf(fract_(th * INV2PI)); }

typedef __bf16 bf16x8 __attribute__((ext_vector_type(8)));
typedef float f32x4 __attribute__((ext_vector_type(4)));

// ---------------- gather embed rows: emb_g[b,t,c] = embed[ids[b,t]][c] ----------------
__global__ __launch_bounds__(256) void k_gather(const int* __restrict__ ids,
                                                const float* __restrict__ embed,
                                                float* __restrict__ eg) {
    int i = blockIdx.x * 256 + threadIdx.x;      // B*S*256
    int c = i & 255, t = (i >> 8) & 1023, b = i >> 18;
    int id = ids[b * S_ + t];
    eg[i] = embed[(size_t)id * 256 + c];
}

// ---------------- euler scan (sequential over t, contracting) ----------------
// emits f32 sr/si/x plus bf16-split K (row-major) for the MFMA attention.
__global__ __launch_bounds__(128) void k_euler(const float* __restrict__ eg,
                                               float* __restrict__ sr, float* __restrict__ si,
                                               float* __restrict__ x,
                                               __bf16* __restrict__ Kh, __bf16* __restrict__ Kl) {
    int b = blockIdx.x;          // 2 blocks
    int d = threadIdx.x;         // 128
    const float* p0 = eg + (size_t)b * S_ * 256 + d;
    float h = 0.f;               // h_real + h_imag carry
    double tp = 0.0;             // 2*t*PHI mod 2pi
    const double DTP = 2.0 * 1.6180339887498949;
    const double TWO_PI = 6.283185307179586476925286766559;
    float wA[8], bA[8], wB[8], bB[8];
#pragma unroll
    for (int k = 0; k < 8; ++k) { wA[k] = p0[k * 256]; bA[k] = p0[k * 256 + 128]; }
    for (int g = 0; g < 128; ++g) {
        if (g < 127) {
            const float* p = p0 + (size_t)(g + 1) * 8 * 256;
#pragma unroll
            for (int k = 0; k < 8; ++k) { wB[k] = p[k * 256]; bB[k] = p[k * 256 + 128]; }
        }
#pragma unroll
        for (int k = 0; k < 8; ++k) {
            int t = g * 8 + k;
            float inv = 1.f / (1.f + fabsf(wA[k]));
            float th = fmaf(h, inv, 2.f * bA[k] + (float)tp);
            float u = fract_(th * INV2PI);
            float sn = __builtin_amdgcn_sinf(u);
            float cs = __builtin_amdgcn_cosf(u);
            size_t idx = ((size_t)b * S_ + t) * D_ + d;
            sr[idx] = cs; si[idx] = sn; x[idx] = cs + sn;
            size_t ki = ((size_t)b * S_ + t) * 256 + d;
            __bf16 ch = (__bf16)cs; Kh[ki] = ch; Kl[ki] = (__bf16)(cs - (float)ch);
            __bf16 sh2 = (__bf16)sn; Kh[ki + 128] = sh2; Kl[ki + 128] = (__bf16)(sn - (float)sh2);
            h = cs + sn;
            tp += DTP; if (tp >= TWO_PI) tp -= TWO_PI;
        }
#pragma unroll
        for (int k = 0; k < 8; ++k) { wA[k] = wB[k]; bA[k] = bB[k]; }
    }
}

// ---------------- transpose K bf16 (b,S,256) -> KT (b,256,S) for PV's B-operand ----------------
__global__ __launch_bounds__(256) void k_ktrans(const __bf16* __restrict__ Kh, const __bf16* __restrict__ Kl,
                                                __bf16* __restrict__ KTh, __bf16* __restrict__ KTl) {
    __shared__ __bf16 th[32][34], tl[32][34];
    int b = blockIdx.z;
    int t0 = blockIdx.x * 32, d0 = blockIdx.y * 32;
    int lx = threadIdx.x & 31, ly = threadIdx.x >> 5;   // 32 x 8
#pragma unroll
    for (int i = 0; i < 4; ++i) {
        int t = t0 + ly + i * 8;
        th[ly + i * 8][lx] = Kh[((size_t)b * S_ + t) * 256 + d0 + lx];
        tl[ly + i * 8][lx] = Kl[((size_t)b * S_ + t) * 256 + d0 + lx];
    }
    __syncthreads();
#pragma unroll
    for (int i = 0; i < 4; ++i) {
        int d = d0 + ly + i * 8;
        KTh[((size_t)b * 256 + d) * S_ + t0 + lx] = th[lx][ly + i * 8];
        KTl[((size_t)b * 256 + d) * S_ + t0 + lx] = tl[lx][ly + i * 8];
    }
}

// ---------------- Q = cos(states/wl_q + b_q + t*phi) -> bf16 hi/lo, layout (B,H,S,2D) ----------------
__global__ __launch_bounds__(256) void k_q(const float* __restrict__ sr, const float* __restrict__ si,
                                           const float* __restrict__ wq, const float* __restrict__ bq,
                                           __bf16* __restrict__ Qh, __bf16* __restrict__ Ql) {
    int i = blockIdx.x * 256 + threadIdx.x;      // B*H*S*256
    int c = i & 255;
    int s = (i >> 8) & 1023;
    int bh = i >> 18;           // b*H + h
    int h = bh & 1, b = bh >> 1;
    int d = c & 127;
    const float* st = (c < 128) ? sr : si;
    float v = st[((size_t)b * S_ + s) * D_ + d];
    float w = wq[h * D_ + d], bb = bq[h * D_ + d];
    float th = v / (1.f + fabsf(w)) + bb + (float)s * PHI_F;
    float qv = fcos_(th);
    __bf16 hq = (__bf16)qv;
    Qh[i] = hq; Ql[i] = (__bf16)(qv - (float)hq);
}

#define LSTR 40   // 32 k + 8 pad (bf16 elems): row stride 80 B, 16B-aligned, ~2-way banks

// ---------------- scores = Q K^T / 16 via bf16-split MFMA (hh + hl + lh) ----------------
// 128x128 tile, 4 waves of 64x64; causal: skip kt>qt tiles; softmax only reads k<=q.
__global__ __launch_bounds__(256) void k_scores_mfma(const __bf16* __restrict__ Qh, const __bf16* __restrict__ Ql,
                                                     const __bf16* __restrict__ Kh, const __bf16* __restrict__ Kl,
                                                     float* __restrict__ sc) {
    int kt = blockIdx.x, qt = blockIdx.y, bh = blockIdx.z;
    if (kt > qt) return;
    __shared__ __bf16 Ah[128 * LSTR], Al[128 * LSTR], Bh[128 * LSTR], Bl[128 * LSTR];
    int tid = threadIdx.x;
    int wid = tid >> 6, lane = tid & 63;
    int wy = wid >> 1, wx = wid & 1;
    int fl = lane & 15, qq = lane >> 4;
    int srow = tid >> 1, sseg = (tid & 1) * 16;
    const __bf16* qh = Qh + ((size_t)bh * S_ + qt * 128 + srow) * 256 + sseg;
    const __bf16* ql = Ql + ((size_t)bh * S_ + qt * 128 + srow) * 256 + sseg;
    const __bf16* kh = Kh + ((size_t)(bh >> 1) * S_ + kt * 128 + srow) * 256 + sseg;
    const __bf16* kl = Kl + ((size_t)(bh >> 1) * S_ + kt * 128 + srow) * 256 + sseg;
    int lbase = srow * LSTR + sseg;

    f32x4 acc[4][4];
#pragma unroll
    for (int i = 0; i < 4; ++i)
#pragma unroll
        for (int j = 0; j < 4; ++j) { acc[i][j][0] = 0.f; acc[i][j][1] = 0.f; acc[i][j][2] = 0.f; acc[i][j][3] = 0.f; }

    for (int kc = 0; kc < 256; kc += 32) {
        uint4 a0 = *(const uint4*)(qh + kc); uint4 a1 = *(const uint4*)(qh + kc + 8);
        uint4 l0 = *(const uint4*)(ql + kc); uint4 l1 = *(const uint4*)(ql + kc + 8);
        uint4 b0 = *(const uint4*)(kh + kc); uint4 b1 = *(const uint4*)(kh + kc + 8);
        uint4 c0 = *(const uint4*)(kl + kc); uint4 c1 = *(const uint4*)(kl + kc + 8);
        __syncthreads();
        *(uint4*)&Ah[lbase] = a0; *(uint4*)&Ah[lbase + 8] = a1;
        *(uint4*)&Al[lbase] = l0; *(uint4*)&Al[lbase + 8] = l1;
        *(uint4*)&Bh[lbase] = b0; *(uint4*)&Bh[lbase + 8] = b1;
        *(uint4*)&Bl[lbase] = c0; *(uint4*)&Bl[lbase + 8] = c1;
        __syncthreads();
        bf16x8 fah[4], fal[4], fbh[4], fbl[4];
#pragma unroll
        for (int tm = 0; tm < 4; ++tm) {
            int r = (wy * 64 + tm * 16 + fl) * LSTR + qq * 8;
            fah[tm] = *(const bf16x8*)&Ah[r];
            fal[tm] = *(const bf16x8*)&Al[r];
        }
#pragma unroll
        for (int tn = 0; tn < 4; ++tn) {
            int r = (wx * 64 + tn * 16 + fl) * LSTR + qq * 8;
            fbh[tn] = *(const bf16x8*)&Bh[r];
            fbl[tn] = *(const bf16x8*)&Bl[r];
        }
#pragma unroll
        for (int tm = 0; tm < 4; ++tm)
#pragma unroll
            for (int tn = 0; tn < 4; ++tn) {
                acc[tm][tn] = __builtin_amdgcn_mfma_f32_16x16x32_bf16(fah[tm], fbh[tn], acc[tm][tn], 0, 0, 0);
                acc[tm][tn] = __builtin_amdgcn_mfma_f32_16x16x32_bf16(fah[tm], fbl[tn], acc[tm][tn], 0, 0, 0);
                acc[tm][tn] = __builtin_amdgcn_mfma_f32_16x16x32_bf16(fal[tm], fbh[tn], acc[tm][tn], 0, 0, 0);
            }
    }
    // C/D layout: col = lane&15, row = (lane>>4)*4 + reg  [m89/m91-verified]
    const float s16 = 0.0625f;
    float* Cp = sc + (size_t)bh * S_ * S_;
    int grow0 = qt * 128 + wy * 64 + qq * 4;
    int gcol0 = kt * 128 + wx * 64 + fl;
#pragma unroll
    for (int tm = 0; tm < 4; ++tm)
#pragma unroll
        for (int tn = 0; tn < 4; ++tn) {
            size_t base = (size_t)(grow0 + tm * 16) * S_ + gcol0 + tn * 16;
#pragma unroll
            for (int r = 0; r < 4; ++r)
                Cp[base + (size_t)r * S_] = acc[tm][tn][r] * s16;
        }
}

// ---------------- softmax: single read pass; write attn as bf16 hi/lo IN PLACE over the f32 row ----
// row layout after this kernel (viewed as bf16): [0,1024) = hi, [1024,2048) = lo.
// zeros written up to the 128-tile boundary so k_pv_mfma can run unmasked.
__global__ __launch_bounds__(256) void k_softmax(float* __restrict__ sc) {
    int row = blockIdx.x;            // (bh*S + q)
    int q = row & 1023;
    float* r = sc + (size_t)row * S_;
    __bf16* rb = (__bf16*)r;
    int tid = threadIdx.x;
    __shared__ float red[256];
    float v[4];
#pragma unroll
    for (int i = 0; i < 4; ++i) {
        int k = tid + i * 256;
        v[i] = (k <= q) ? r[k] : -1e30f;
    }
    float m = fmaxf(fmaxf(v[0], v[1]), fmaxf(v[2], v[3]));
    red[tid] = m; __syncthreads();
    for (int s = 128; s > 0; s >>= 1) { if (tid < s) red[tid] = fmaxf(red[tid], red[tid + s]); __syncthreads(); }
    m = red[0]; __syncthreads();
    float e[4]; float sum = 0.f;
#pragma unroll
    for (int i = 0; i < 4; ++i) {
        int k = tid + i * 256;
        e[i] = (k <= q) ? __expf(v[i] - m) : 0.f;
        sum += e[i];
    }
    red[tid] = sum; __syncthreads();
    for (int s = 128; s > 0; s >>= 1) { if (tid < s) red[tid] += red[tid + s]; __syncthreads(); }
    float rs = 1.f / red[0];
    // all f32 reads of this row happened before the barriers above; safe to overwrite as bf16.
#pragma unroll
    for (int i = 0; i < 4; ++i) {
        int k = tid + i * 256;
        if (k <= q) {
            float p = e[i] * rs;
            __bf16 h = (__bf16)p;
            rb[k] = h;
            rb[1024 + k] = (__bf16)(p - (float)h);
        }
    }
    int kz = ((q >> 7) + 1) << 7;    // tile boundary covering this row
    for (int k = q + 1 + tid; k < kz; k += 256) { rb[k] = (__bf16)0.f; rb[1024 + k] = (__bf16)0.f; }
}

// ---------------- retrieved = attn @ K via bf16-split MFMA; K loop capped at causal boundary ------
__global__ __launch_bounds__(256) void k_pv_mfma(const float* __restrict__ SCf,
                                                 const __bf16* __restrict__ KTh, const __bf16* __restrict__ KTl,
                                                 float* __restrict__ R) {
    __shared__ __bf16 Ah[128 * LSTR], Al[128 * LSTR], Bh[128 * LSTR], Bl[128 * LSTR];
    int nt = blockIdx.x, qt = blockIdx.y, bh = blockIdx.z;
    int tid = threadIdx.x;
    int wid = tid >> 6, lane = tid & 63;
    int wy = wid >> 1, wx = wid & 1;
    int fl = lane & 15, qq = lane >> 4;
    int srow = tid >> 1, sseg = (tid & 1) * 16;
    const __bf16* att = (const __bf16*)(SCf + (size_t)bh * S_ * S_);   // rows of 2048 bf16 (hi|lo)
    const __bf16* ah = att + (size_t)(qt * 128 + srow) * 2048 + sseg;
    const __bf16* al = ah + 1024;
    const __bf16* bh_p = KTh + ((size_t)(bh >> 1) * 256 + nt * 128 + srow) * S_ + sseg;
    const __bf16* bl_p = KTl + ((size_t)(bh >> 1) * 256 + nt * 128 + srow) * S_ + sseg;
    int lbase = srow * LSTR + sseg;

    f32x4 acc[4][4];
#pragma unroll
    for (int i = 0; i < 4; ++i)
#pragma unroll
        for (int j = 0; j < 4; ++j) { acc[i][j][0] = 0.f; acc[i][j][1] = 0.f; acc[i][j][2] = 0.f; acc[i][j][3] = 0.f; }

    int kmax = qt * 128 + 128;
    for (int kc = 0; kc < kmax; kc += 32) {
        uint4 a0 = *(const uint4*)(ah + kc); uint4 a1 = *(const uint4*)(ah + kc + 8);
        uint4 l0 = *(const uint4*)(al + kc); uint4 l1 = *(const uint4*)(al + kc + 8);
        uint4 b0 = *(const uint4*)(bh_p + kc); uint4 b1 = *(const uint4*)(bh_p + kc + 8);
        uint4 c0 = *(const uint4*)(bl_p + kc); uint4 c1 = *(const uint4*)(bl_p + kc + 8);
        __syncthreads();
        *(uint4*)&Ah[lbase] = a0; *(uint4*)&Ah[lbase + 8] = a1;
        *(uint4*)&Al[lbase] = l0; *(uint4*)&Al[lbase + 8] = l1;
        *(uint4*)&Bh[lbase] = b0; *(uint4*)&Bh[lbase + 8] = b1;
        *(uint4*)&Bl[lbase] = c0; *(uint4*)&Bl[lbase + 8] = c1;
        __syncthreads();
        bf16x8 fah[4], fal[4], fbh[4], fbl[4];
#pragma unroll
        for (int tm = 0; tm < 4; ++tm) {
            int r = (wy * 64 + tm * 16 + fl) * LSTR + qq * 8;
            fah[tm] = *(const bf16x8*)&Ah[r];
            fal[tm] = *(const bf16x8*)&Al[r];
        }
#pragma unroll
        for (int tn = 0; tn < 4; ++tn) {
            int r = (wx * 64 + tn * 16 + fl) * LSTR + qq * 8;
            fbh[tn] = *(const bf16x8*)&Bh[r];
            fbl[tn] = *(const bf16x8*)&Bl[r];
        }
#pragma unroll
        for (int tm = 0; tm < 4; ++tm)
#pragma unroll
            for (int tn = 0; tn < 4; ++tn) {
                acc[tm][tn] = __builtin_amdgcn_mfma_f32_16x16x32_bf16(fah[tm], fbh[tn], acc[tm][tn], 0, 0, 0);
                acc[tm][tn] = __builtin_amdgcn_mfma_f32_16x16x32_bf16(fah[tm], fbl[tn], acc[tm][tn], 0, 0, 0);
                acc[tm][tn] = __builtin_amdgcn_mfma_f32_16x16x32_bf16(fal[tm], fbh[tn], acc[tm][tn], 0, 0, 0);
            }
    }
    float* Rp = R + (size_t)bh * S_ * 256;
    int grow0 = qt * 128 + wy * 64 + qq * 4;
    int gcol0 = nt * 128 + wx * 64 + fl;
#pragma unroll
    for (int tm = 0; tm < 4; ++tm)
#pragma unroll
        for (int tn = 0; tn < 4; ++tn) {
            size_t base = (size_t)(grow0 + tm * 16) * 256 + gcol0 + tn * 16;
#pragma unroll
            for (int r = 0; r < 4; ++r)
                Rp[base + (size_t)r * 256] = acc[tm][tn][r];
        }
}

// ---------------- EMA as 64-tap FIR ((1-a)^64 ~ 2e-21), heads+halves summed ----------------
__global__ __launch_bounds__(256) void k_ema(const float* __restrict__ R,
                                             const float* __restrict__ ap,
                                             float* __restrict__ comb) {
    int blk = blockIdx.x;            // b*S + t
    int b = blk >> 10, t = blk & 1023;
    int dim = threadIdx.x;           // 256
    __shared__ float wsh[2][64];
    __shared__ float sh[256];
    if (dim < 128) {
        int h = dim >> 6, j = dim & 63;
        float a = 1.f / (1.f + __expf(-ap[h]));
        float om = 1.f - a;
        wsh[h][j] = a * exp2f((float)j * log2f(om));
    }
    __syncthreads();
    int jmax = t < 63 ? t : 63;
    float acc = 0.f;
    for (int h = 0; h < 2; ++h) {
        const float* base = R + ((size_t)(b * 2 + h) * S_ + t) * 256 + dim;
        float s = 0.f;
        for (int j = 0; j <= jmax; ++j) s = fmaf(wsh[h][j], base[-j * 256], s);
        acc += s;
    }
    sh[dim] = acc;
    __syncthreads();
    if (dim < 128) comb[((size_t)b * S_ + t) * D_ + dim] = sh[dim] + sh[dim + 128];
}

// ---------------- FFN prep: transpose params to (D,N) / (N,D) ----------------
__global__ __launch_bounds__(256) void k_prep(const float* __restrict__ W, const float* __restrict__ Bp,
                                              const float* __restrict__ ac, const float* __restrict__ as2,
                                              const float* __restrict__ pc, const float* __restrict__ ps,
                                              float* __restrict__ iwT, float* __restrict__ bpT,
                                              float* __restrict__ acT, float* __restrict__ asT,
                                              float* __restrict__ pcT, float* __restrict__ psT) {
    int i = blockIdx.x * 256 + threadIdx.x;    // L*N*D, i = (l,n,d)
    int d = i & 127, n = (i >> 7) & 255, l = i >> 15;
    int ti = (l * 128 + d) * 256 + n;          // (l,d,n)
    iwT[ti] = 1.f / (1.f + fabsf(W[i]));
    bpT[ti] = Bp[i];
    acT[ti] = ac[i];
    asT[ti] = as2[i];
    // proj_cos is (L,D,N): element (l,d,n) sits at ti -> write (L,N,D)
    pcT[(l * 256 + n) * 128 + d] = pc[ti];
    psT[(l * 256 + n) * 128 + d] = ps[ti];
}

// ---------------- FFN phase 1: cos_sum/sin_sum, 8 rows per block ----------------
__global__ __launch_bounds__(256) void k_ffn1(const float* __restrict__ x,
                                              const float* __restrict__ iwT, const float* __restrict__ bpT,
                                              const float* __restrict__ acT, const float* __restrict__ asT,
                                              float* __restrict__ cs, float* __restrict__ ss) {
    int row0 = blockIdx.x * 8;
    int n = threadIdx.x;             // 256
    __shared__ float xs[8][128];
#pragma unroll
    for (int i = 0; i < 4; ++i) {
        int idx = n + i * 256;
        xs[idx >> 7][idx & 127] = x[(size_t)row0 * D_ + idx];
    }
    __syncthreads();
    float ac_[8] = {}, as_[8] = {};
    for (int d = 0; d < 128; ++d) {
        float iw = iwT[d * 256 + n];
        float bp = bpT[d * 256 + n];
        float wc = acT[d * 256 + n];
        float ws2 = asT[d * 256 + n];
#pragma unroll
        for (int r = 0; r < 8; ++r) {
            float th = fmaf(xs[r][d], iw, bp);
            float u = fract_(th * INV2PI);
            ac_[r] = fmaf(__builtin_amdgcn_cosf(u), wc, ac_[r]);
            as_[r] = fmaf(__builtin_amdgcn_sinf(u), ws2, as_[r]);
        }
    }
#pragma unroll
    for (int r = 0; r < 8; ++r) {
        cs[(size_t)(row0 + r) * 256 + n] = ac_[r];
        ss[(size_t)(row0 + r) * 256 + n] = as_[r];
    }
}

// ---------------- FFN phase 2: proj + silu, 8 rows per block ----------------
__global__ __launch_bounds__(128) void k_ffn2(const float* __restrict__ cs, const float* __restrict__ ss,
                                              const float* __restrict__ pcT, const float* __restrict__ psT,
                                              float* __restrict__ res) {
    int row0 = blockIdx.x * 8;
    int d = threadIdx.x;             // 128
    __shared__ float csh[8][256], ssh[8][256];
#pragma unroll
    for (int i = 0; i < 16; ++i) {
        int idx = d + i * 128;
        csh[idx >> 8][idx & 255] = cs[(size_t)row0 * 256 + idx];
        ssh[idx >> 8][idx & 255] = ss[(size_t)row0 * 256 + idx];
    }
    __syncthreads();
    float acc[8] = {};
    for (int nn = 0; nn < 256; ++nn) {
        float pc = pcT[nn * 128 + d], ps = psT[nn * 128 + d];
#pragma unroll
        for (int r = 0; r < 8; ++r)
            acc[r] = fmaf(csh[r][nn], pc, fmaf(ssh[r][nn], ps, acc[r]));
    }
#pragma unroll
    for (int r = 0; r < 8; ++r) {
        float v = acc[r];
        res[(size_t)(row0 + r) * D_ + d] = v / (1.f + __expf(-v));   // silu
    }
}

// ---------------- x += es*(cos+sin)((comb/wl_out)+bout) + rs*res ----------------
__global__ __launch_bounds__(256) void k_update(float* __restrict__ x, const float* __restrict__ comb,
                                                const float* __restrict__ res,
                                                const float* __restrict__ wout, const float* __restrict__ bout,
                                                const float* __restrict__ esp, const float* __restrict__ rsp) {
    int i = blockIdx.x * 256 + threadIdx.x;    // B*S*D
    int d = i & 127;
    float wl = 1.f + fabsf(wout[d]);
    float th = comb[i] / wl + bout[d];
    float u = fract_(th * INV2PI);
    float echo = __builtin_amdgcn_cosf(u) + __builtin_amdgcn_sinf(u);
    x[i] += esp[0] * echo + rsp[0] * res[i];
}

// ---------------- split f32 -> bf16 hi + bf16 lo for X (2048x128) and P (32000x128) ----------------
__global__ __launch_bounds__(256) void k_cvt(const float* __restrict__ X, const float* __restrict__ P,
                                             __bf16* __restrict__ Xh, __bf16* __restrict__ Xl,
                                             __bf16* __restrict__ Ph, __bf16* __restrict__ Pl) {
    int i = blockIdx.x * 256 + threadIdx.x;    // 0 .. (2048+32000)*128-1
    const int NX = 2048 * 128;
    float v; __bf16 *h, *l; int j;
    if (i < NX) { v = X[i]; h = Xh; l = Xl; j = i; }
    else { v = P[i - NX]; h = Ph; l = Pl; j = i - NX; }
    __bf16 hi = (__bf16)v;
    float lo = v - (float)hi;
    h[j] = hi;
    l[j] = (__bf16)lo;
}

// ---------------- out = X @ P^T via bf16-split MFMA (hh + hl + lh) ----------------
// block tile 128(M) x 128(N), 4 waves each 64x64 (4x4 of 16x16x32 mfma), K chunked by 32.
__global__ __launch_bounds__(256) void k_out_mfma(const __bf16* __restrict__ Xh, const __bf16* __restrict__ Xl,
                                                  const __bf16* __restrict__ Ph, const __bf16* __restrict__ Pl,
                                                  float* __restrict__ out) {
    __shared__ __bf16 Ah[128 * LSTR], Al[128 * LSTR], Bh[128 * LSTR], Bl[128 * LSTR];
    int mt = blockIdx.x, nt = blockIdx.y;
    int tid = threadIdx.x;
    int wid = tid >> 6, lane = tid & 63;
    int wy = wid >> 1, wx = wid & 1;
    int fl = lane & 15, q = lane >> 4;
    // staging map: 2 threads per row, 16 bf16 each
    int srow = tid >> 1, sseg = (tid & 1) * 16;
    const __bf16* xh = Xh + (size_t)(mt * 128 + srow) * 128 + sseg;
    const __bf16* xl = Xl + (size_t)(mt * 128 + srow) * 128 + sseg;
    const __bf16* ph = Ph + (size_t)(nt * 128 + srow) * 128 + sseg;
    const __bf16* pl = Pl + (size_t)(nt * 128 + srow) * 128 + sseg;
    int lbase = srow * LSTR + sseg;

    f32x4 acc[4][4];
#pragma unroll
    for (int i = 0; i < 4; ++i)
#pragma unroll
        for (int j = 0; j < 4; ++j) { acc[i][j][0] = 0.f; acc[i][j][1] = 0.f; acc[i][j][2] = 0.f; acc[i][j][3] = 0.f; }

    for (int kc = 0; kc < 128; kc += 32) {
        uint4 vxh0 = *(const uint4*)(xh + kc); uint4 vxh1 = *(const uint4*)(xh + kc + 8);
        uint4 vxl0 = *(const uint4*)(xl + kc); uint4 vxl1 = *(const uint4*)(xl + kc + 8);
        uint4 vph0 = *(const uint4*)(ph + kc); uint4 vph1 = *(const uint4*)(ph + kc + 8);
        uint4 vpl0 = *(const uint4*)(pl + kc); uint4 vpl1 = *(const uint4*)(pl + kc + 8);
        __syncthreads();
        *(uint4*)&Ah[lbase] = vxh0; *(uint4*)&Ah[lbase + 8] = vxh1;
        *(uint4*)&Al[lbase] = vxl0; *(uint4*)&Al[lbase + 8] = vxl1;
        *(uint4*)&Bh[lbase] = vph0; *(uint4*)&Bh[lbase + 8] = vph1;
        *(uint4*)&Bl[lbase] = vpl0; *(uint4*)&Bl[lbase + 8] = vpl1;
        __syncthreads();
        bf16x8 ah[4], al[4], bh[4], bl[4];
#pragma unroll
        for (int tm = 0; tm < 4; ++tm) {
            int r = (wy * 64 + tm * 16 + fl) * LSTR + q * 8;
            ah[tm] = *(const bf16x8*)&Ah[r];
            al[tm] = *(const bf16x8*)&Al[r];
        }
#pragma unroll
        for (int tn = 0; tn < 4; ++tn) {
            int r = (wx * 64 + tn * 16 + fl) * LSTR + q * 8;
            bh[tn] = *(const bf16x8*)&Bh[r];
            bl[tn] = *(const bf16x8*)&Bl[r];
        }
#pragma unroll
        for (int tm = 0; tm < 4; ++tm)
#pragma unroll
            for (int tn = 0; tn < 4; ++tn) {
                acc[tm][tn] = __builtin_amdgcn_mfma_f32_16x16x32_bf16(ah[tm], bh[tn], acc[tm][tn], 0, 0, 0);
                acc[tm][tn] = __builtin_amdgcn_mfma_f32_16x16x32_bf16(ah[tm], bl[tn], acc[tm][tn], 0, 0, 0);
                acc[tm][tn] = __builtin_amdgcn_mfma_f32_16x16x32_bf16(al[tm], bh[tn], acc[tm][tn], 0, 0, 0);
            }
    }
    // C/D layout: col = lane&15, row = (lane>>4)*4 + reg  [m89/m91-verified]
    int grow0 = mt * 128 + wy * 64 + q * 4;
    int gcol0 = nt * 128 + wx * 64 + fl;
#pragma unroll
    for (int tm = 0; tm < 4; ++tm)
#pragma unroll
        for (int tn = 0; tn < 4; ++tn) {
            size_t base = (size_t)(grow0 + tm * 16) * V_ + gcol0 + tn * 16;
#pragma unroll
            for (int r = 0; r < 4; ++r)
                out[base + (size_t)r * V_] = acc[tm][tn][r];
        }
}

extern "C" void kernel_launch(void* const* d_in, const int* in_sizes, int n_in,
                              void* d_out, int out_size, void* d_ws, size_t ws_size,
                              hipStream_t stream) {
    const int* ids = (const int*)d_in[0];
    const float* embed = (const float*)d_in[1];
    const float* wq = (const float*)d_in[2];     // (L,H,D)
    const float* bq = (const float*)d_in[3];
    const float* alpha = (const float*)d_in[4];  // (L,H)
    const float* wout = (const float*)d_in[5];   // (L,D)
    const float* bout = (const float*)d_in[6];
    const float* ffnW = (const float*)d_in[7];   // (L,N,D)
    const float* ffnB = (const float*)d_in[8];
    const float* acos_ = (const float*)d_in[9];
    const float* asin_ = (const float*)d_in[10];
    const float* pcos = (const float*)d_in[11];  // (L,D,N)
    const float* psin = (const float*)d_in[12];
    const float* escl = (const float*)d_in[13];  // (L,)
    const float* rscl = (const float*)d_in[14];
    const float* oprj = (const float*)d_in[15];  // (V,D)
    float* out = (float*)d_out;
    float* ws = (float*)d_ws;

    // workspace layout (floats) — same footprint as previous version
    float* EG = ws;                       // B*S*256      = 524288 (dead after euler -> holds KT bf16)
    float* SR = EG + 524288;              // B*S*D        = 262144
    float* SI = SR + 262144;
    float* X  = SI + 262144;
    float* KB = X + 262144;               // 524288 f32 -> Kh/Kl bf16 (row-major)
    float* Q  = KB + 524288;              // 1048576 f32 -> Qh/Ql bf16
    float* SC = Q + 1048576;              // B*H*S*S      = 4194304 (f32 scores, then in-place bf16 attn)
    float* RT = SC + 4194304;             // B*H*S*256    = 1048576
    float* CB = RT + 1048576;             // B*S*D        = 262144
    float* CS = CB + 262144;              // B*S*N        = 524288
    float* SS = CS + 524288;
    float* RS = SS + 524288;              // B*S*D        = 262144
    float* T_IW = RS + 262144;            // 6 x L*D*N (=65536 each)
    float* T_BP = T_IW + 65536;
    float* T_AC = T_BP + 65536;
    float* T_AS = T_AC + 65536;
    float* T_PC = T_AS + 65536;
    float* T_PS = T_PC + 65536;
    // bf16 views
    __bf16* KH = (__bf16*)KB;             // (B,S,256) hi
    __bf16* KL = KH + 524288;             // lo
    __bf16* QH = (__bf16*)Q;              // (B*H,S,256) hi
    __bf16* QL = QH + 1048576;            // lo
    __bf16* KTH = (__bf16*)EG;            // (B,256,S) hi — overlays dead EG
    __bf16* KTL = KTH + 524288;           // lo
    // bf16-split buffers for k_out, overlaid on Q..SC (dead by the time k_cvt runs)
    __bf16* XH = (__bf16*)Q;              // 262144 bf16
    __bf16* XL = XH + 262144;
    __bf16* PH = XL + 262144;             // 4096000 bf16
    __bf16* PL = PH + 4096000;

    k_prep<<<256, 256, 0, stream>>>(ffnW, ffnB, acos_, asin_, pcos, psin,
                                    T_IW, T_BP, T_AC, T_AS, T_PC, T_PS);
    k_gather<<<2048, 256, 0, stream>>>(ids, embed, EG);
    k_euler<<<2, 128, 0, stream>>>(EG, SR, SI, X, KH, KL);
    k_ktrans<<<dim3(32, 8, 2), 256, 0, stream>>>(KH, KL, KTH, KTL);

    for (int l = 0; l < L_; ++l) {
        k_q<<<4096, 256, 0, stream>>>(SR, SI, wq + l * H_ * D_, bq + l * H_ * D_, QH, QL);
        k_scores_mfma<<<dim3(8, 8, 4), 256, 0, stream>>>(QH, QL, KH, KL, SC);
        k_softmax<<<4096, 256, 0, stream>>>(SC);
        k_pv_mfma<<<dim3(2, 8, 4), 256, 0, stream>>>(SC, KTH, KTL, RT);
        k_ema<<<2048, 256, 0, stream>>>(RT, alpha + l * H_, CB);
        k_ffn1<<<256, 256, 0, stream>>>(X, T_IW + l * 32768, T_BP + l * 32768,
                                        T_AC + l * 32768, T_AS + l * 32768, CS, SS);
        k_ffn2<<<256, 128, 0, stream>>>(CS, SS, T_PC + l * 32768, T_PS + l * 32768, RS);
        k_update<<<1024, 256, 0, stream>>>(X, CB, RS, wout + l * D_, bout + l * D_,
                                           escl + l, rscl + l);
    }
    k_cvt<<<17024, 256, 0, stream>>>(X, oprj, XH, XL, PH, PL);
    k_out_mfma<<<dim3(16, 250), 256, 0, stream>>>(XH, XL, PH, PL, out);
}

// Round 5
// 901.398 us; speedup vs baseline: 1.0381x; 1.0381x over previous
//
#include <hip/hip_runtime.h>
#include <math.h>

#define B_ 2
#define S_ 1024
#define D_ 128
#define N_ 256
#define L_ 2
#define H_ 2
#define V_ 32000

#define INV2PI 0.15915494309189535f
#define PHI_F 1.61803398874989484f

__device__ __forceinline__ float fract_(float x) { return x - floorf(x); }
// v_sin/v_cos take revolutions; reduce first.
__device__ __forceinline__ float fsin_(float th) { return __builtin_amdgcn_sinf(fract_(th * INV2PI)); }
__device__ __forceinline__ float fcos_(float th) { return __builtin_amdgcn_cosf(fract_(th * INV2PI)); }

typedef __bf16 bf16x8 __attribute__((ext_vector_type(8)));
typedef float f32x4 __attribute__((ext_vector_type(4)));

// ---------------- fused gather (blocks 0..2047) + FFN param prep (blocks 2048..2303) ----------------
__global__ __launch_bounds__(256) void k_gp(const int* __restrict__ ids, const float* __restrict__ embed,
                                            float* __restrict__ eg,
                                            const float* __restrict__ W, const float* __restrict__ Bp,
                                            const float* __restrict__ ac, const float* __restrict__ as2,
                                            const float* __restrict__ pc, const float* __restrict__ ps,
                                            float* __restrict__ iwT, float* __restrict__ bpT,
                                            float* __restrict__ acT, float* __restrict__ asT,
                                            float* __restrict__ pcT, float* __restrict__ psT) {
    int blk = blockIdx.x;
    if (blk < 2048) {
        int i = blk * 256 + threadIdx.x;             // B*S*256
        int c = i & 255, t = (i >> 8) & 1023, b = i >> 18;
        eg[i] = embed[(size_t)ids[b * S_ + t] * 256 + c];
    } else {
        int i = (blk - 2048) * 256 + threadIdx.x;    // L*N*D = 65536
        int d = i & 127, n = (i >> 7) & 255, l = i >> 15;
        int ti = (l * 128 + d) * 256 + n;            // (l,d,n)
        iwT[ti] = 1.f / (1.f + fabsf(W[i]));
        bpT[ti] = Bp[i];
        acT[ti] = ac[i];
        asT[ti] = as2[i];
        // proj_cos is (L,D,N): element (l,d,n) sits at ti -> write (L,N,D)
        pcT[(l * 256 + n) * 128 + d] = pc[ti];
        psT[(l * 256 + n) * 128 + d] = ps[ti];
    }
}

// ---------------- euler scan; emits sr/si/x f32, K row-major bf16 hi/lo AND K^T bf16 hi/lo --------
__global__ __launch_bounds__(128) void k_euler(const float* __restrict__ eg,
                                               float* __restrict__ sr, float* __restrict__ si,
                                               float* __restrict__ x,
                                               __bf16* __restrict__ Kh, __bf16* __restrict__ Kl,
                                               __bf16* __restrict__ KTh, __bf16* __restrict__ KTl) {
    int b = blockIdx.x;          // 2 blocks
    int d = threadIdx.x;         // 128
    const float* p0 = eg + (size_t)b * S_ * 256 + d;
    float h = 0.f;               // h_real + h_imag carry
    double tp = 0.0;             // 2*t*PHI mod 2pi
    const double DTP = 2.0 * 1.6180339887498949;
    const double TWO_PI = 6.283185307179586476925286766559;
    float wA[8], bA[8], wB[8], bB[8];
#pragma unroll
    for (int k = 0; k < 8; ++k) { wA[k] = p0[k * 256]; bA[k] = p0[k * 256 + 128]; }
    for (int g = 0; g < 128; ++g) {
        if (g < 127) {
            const float* p = p0 + (size_t)(g + 1) * 8 * 256;
#pragma unroll
            for (int k = 0; k < 8; ++k) { wB[k] = p[k * 256]; bB[k] = p[k * 256 + 128]; }
        }
#pragma unroll
        for (int k = 0; k < 8; ++k) {
            int t = g * 8 + k;
            float inv = 1.f / (1.f + fabsf(wA[k]));
            float th = fmaf(h, inv, 2.f * bA[k] + (float)tp);
            float u = fract_(th * INV2PI);
            float sn = __builtin_amdgcn_sinf(u);
            float cs = __builtin_amdgcn_cosf(u);
            size_t idx = ((size_t)b * S_ + t) * D_ + d;
            sr[idx] = cs; si[idx] = sn; x[idx] = cs + sn;
            __bf16 ch = (__bf16)cs; __bf16 cl = (__bf16)(cs - (float)ch);
            __bf16 sh2 = (__bf16)sn; __bf16 sl = (__bf16)(sn - (float)sh2);
            size_t ki = ((size_t)b * S_ + t) * 256 + d;
            Kh[ki] = ch; Kl[ki] = cl;
            Kh[ki + 128] = sh2; Kl[ki + 128] = sl;
            size_t kt1 = ((size_t)b * 256 + d) * S_ + t;          // KT[b][d][t]
            size_t kt2 = ((size_t)b * 256 + d + 128) * S_ + t;    // KT[b][d+128][t]
            KTh[kt1] = ch; KTl[kt1] = cl;
            KTh[kt2] = sh2; KTl[kt2] = sl;
            h = cs + sn;
            tp += DTP; if (tp >= TWO_PI) tp -= TWO_PI;
        }
#pragma unroll
        for (int k = 0; k < 8; ++k) { wA[k] = wB[k]; bA[k] = bB[k]; }
    }
}

// ---------------- Q for BOTH layers: bf16 hi/lo, layout (l)(B,H,S,2D) ----------------
__global__ __launch_bounds__(256) void k_qq(const float* __restrict__ sr, const float* __restrict__ si,
                                            const float* __restrict__ wq, const float* __restrict__ bq,
                                            __bf16* __restrict__ Qh0, __bf16* __restrict__ Ql0,
                                            __bf16* __restrict__ Qh1, __bf16* __restrict__ Ql1) {
    int i = blockIdx.x * 256 + threadIdx.x;      // 2 * 2^20
    int l = i >> 20;
    int j = i & 0xFFFFF;
    int c = j & 255;
    int s = (j >> 8) & 1023;
    int bh = j >> 18;           // b*H + h
    int h = bh & 1, b = bh >> 1;
    int d = c & 127;
    const float* st = (c < 128) ? sr : si;
    float v = st[((size_t)b * S_ + s) * D_ + d];
    float w = wq[(l * H_ + h) * D_ + d], bb = bq[(l * H_ + h) * D_ + d];
    float th = v / (1.f + fabsf(w)) + bb + (float)s * PHI_F;
    float qv = fcos_(th);
    __bf16 hq = (__bf16)qv;
    __bf16 lq = (__bf16)(qv - (float)hq);
    if (l == 0) { Qh0[j] = hq; Ql0[j] = lq; }
    else        { Qh1[j] = hq; Ql1[j] = lq; }
}

#define LSTR 40   // 32 k + 8 pad (bf16 elems): row stride 80 B, 16B-aligned, ~2-way banks

// ---------------- scores = Q K^T / 16 via bf16-split MFMA (hh + hl + lh), f32 out ----------------
__global__ __launch_bounds__(256) void k_scores_mfma(const __bf16* __restrict__ Qh, const __bf16* __restrict__ Ql,
                                                     const __bf16* __restrict__ Kh, const __bf16* __restrict__ Kl,
                                                     float* __restrict__ sc) {
    int kt = blockIdx.x, qt = blockIdx.y, bh = blockIdx.z;
    if (kt > qt) return;
    __shared__ __bf16 Ah[128 * LSTR], Al[128 * LSTR], Bh[128 * LSTR], Bl[128 * LSTR];
    int tid = threadIdx.x;
    int wid = tid >> 6, lane = tid & 63;
    int wy = wid >> 1, wx = wid & 1;
    int fl = lane & 15, qq = lane >> 4;
    int srow = tid >> 1, sseg = (tid & 1) * 16;
    const __bf16* qh = Qh + ((size_t)bh * S_ + qt * 128 + srow) * 256 + sseg;
    const __bf16* ql = Ql + ((size_t)bh * S_ + qt * 128 + srow) * 256 + sseg;
    const __bf16* kh = Kh + ((size_t)(bh >> 1) * S_ + kt * 128 + srow) * 256 + sseg;
    const __bf16* kl = Kl + ((size_t)(bh >> 1) * S_ + kt * 128 + srow) * 256 + sseg;
    int lbase = srow * LSTR + sseg;

    f32x4 acc[4][4];
#pragma unroll
    for (int i = 0; i < 4; ++i)
#pragma unroll
        for (int j = 0; j < 4; ++j) { acc[i][j][0] = 0.f; acc[i][j][1] = 0.f; acc[i][j][2] = 0.f; acc[i][j][3] = 0.f; }

    for (int kc = 0; kc < 256; kc += 32) {
        uint4 a0 = *(const uint4*)(qh + kc); uint4 a1 = *(const uint4*)(qh + kc + 8);
        uint4 l0 = *(const uint4*)(ql + kc); uint4 l1 = *(const uint4*)(ql + kc + 8);
        uint4 b0 = *(const uint4*)(kh + kc); uint4 b1 = *(const uint4*)(kh + kc + 8);
        uint4 c0 = *(const uint4*)(kl + kc); uint4 c1 = *(const uint4*)(kl + kc + 8);
        __syncthreads();
        *(uint4*)&Ah[lbase] = a0; *(uint4*)&Ah[lbase + 8] = a1;
        *(uint4*)&Al[lbase] = l0; *(uint4*)&Al[lbase + 8] = l1;
        *(uint4*)&Bh[lbase] = b0; *(uint4*)&Bh[lbase + 8] = b1;
        *(uint4*)&Bl[lbase] = c0; *(uint4*)&Bl[lbase + 8] = c1;
        __syncthreads();
        bf16x8 fah[4], fal[4], fbh[4], fbl[4];
#pragma unroll
        for (int tm = 0; tm < 4; ++tm) {
            int r = (wy * 64 + tm * 16 + fl) * LSTR + qq * 8;
            fah[tm] = *(const bf16x8*)&Ah[r];
            fal[tm] = *(const bf16x8*)&Al[r];
        }
#pragma unroll
        for (int tn = 0; tn < 4; ++tn) {
            int r = (wx * 64 + tn * 16 + fl) * LSTR + qq * 8;
            fbh[tn] = *(const bf16x8*)&Bh[r];
            fbl[tn] = *(const bf16x8*)&Bl[r];
        }
#pragma unroll
        for (int tm = 0; tm < 4; ++tm)
#pragma unroll
            for (int tn = 0; tn < 4; ++tn) {
                acc[tm][tn] = __builtin_amdgcn_mfma_f32_16x16x32_bf16(fah[tm], fbh[tn], acc[tm][tn], 0, 0, 0);
                acc[tm][tn] = __builtin_amdgcn_mfma_f32_16x16x32_bf16(fah[tm], fbl[tn], acc[tm][tn], 0, 0, 0);
                acc[tm][tn] = __builtin_amdgcn_mfma_f32_16x16x32_bf16(fal[tm], fbh[tn], acc[tm][tn], 0, 0, 0);
            }
    }
    // C/D layout: col = lane&15, row = (lane>>4)*4 + reg  [m89/m91-verified]
    const float s16 = 0.0625f;
    float* Cp = sc + (size_t)bh * S_ * S_;
    int grow0 = qt * 128 + wy * 64 + qq * 4;
    int gcol0 = kt * 128 + wx * 64 + fl;
#pragma unroll
    for (int tm = 0; tm < 4; ++tm)
#pragma unroll
        for (int tn = 0; tn < 4; ++tn) {
            size_t base = (size_t)(grow0 + tm * 16) * S_ + gcol0 + tn * 16;
#pragma unroll
            for (int r = 0; r < 4; ++r)
                Cp[base + (size_t)r * S_] = acc[tm][tn][r] * s16;
        }
}

// ---------------- fused softmax + PV: row stats (2 thr/row) then exp-transform in A-staging -------
__global__ __launch_bounds__(256) void k_pv_sm(const float* __restrict__ SCf,
                                               const __bf16* __restrict__ KTh, const __bf16* __restrict__ KTl,
                                               float* __restrict__ R) {
    __shared__ __bf16 Ah[128 * LSTR], Al[128 * LSTR], Bh[128 * LSTR], Bl[128 * LSTR];
    __shared__ float mrow[128], rrow[128];
    int nt = blockIdx.x, qt = blockIdx.y, bh = blockIdx.z;
    int tid = threadIdx.x;
    int wid = tid >> 6, lane = tid & 63;
    int wy = wid >> 1, wx = wid & 1;
    int fl = lane & 15, qq = lane >> 4;
    int srow = tid >> 1, half = tid & 1, sseg = half * 16;
    const float* Sp = SCf + (size_t)bh * S_ * S_;
    int kceil = qt * 128 + 128;
    // ---- row stats: max then sum (masked at causal boundary) ----
    {
        int r = srow;
        int q = qt * 128 + r;
        const float* rp = Sp + (size_t)q * S_;
        float m = -3e38f;
        for (int c = half * 4; c < kceil; c += 8) {
            float4 v = *(const float4*)&rp[c];
            if (c + 0 <= q) m = fmaxf(m, v.x);
            if (c + 1 <= q) m = fmaxf(m, v.y);
            if (c + 2 <= q) m = fmaxf(m, v.z);
            if (c + 3 <= q) m = fmaxf(m, v.w);
        }
        m = fmaxf(m, __shfl_xor(m, 1));
        float s = 0.f;
        for (int c = half * 4; c < kceil; c += 8) {
            float4 v = *(const float4*)&rp[c];
            if (c + 0 <= q) s += __expf(v.x - m);
            if (c + 1 <= q) s += __expf(v.y - m);
            if (c + 2 <= q) s += __expf(v.z - m);
            if (c + 3 <= q) s += __expf(v.w - m);
        }
        s += __shfl_xor(s, 1);
        mrow[r] = m;
        rrow[r] = 1.f / s;
    }
    __syncthreads();
    float mR = mrow[srow], rsR = rrow[srow];
    int qrow = qt * 128 + srow;
    const float* ap = Sp + (size_t)qrow * S_ + sseg;
    const __bf16* bh_p = KTh + ((size_t)(bh >> 1) * 256 + nt * 128 + srow) * S_ + sseg;
    const __bf16* bl_p = KTl + ((size_t)(bh >> 1) * 256 + nt * 128 + srow) * S_ + sseg;
    int lbase = srow * LSTR + sseg;

    f32x4 acc[4][4];
#pragma unroll
    for (int i = 0; i < 4; ++i)
#pragma unroll
        for (int j = 0; j < 4; ++j) { acc[i][j][0] = 0.f; acc[i][j][1] = 0.f; acc[i][j][2] = 0.f; acc[i][j][3] = 0.f; }

    for (int kc = 0; kc < kceil; kc += 32) {
        float4 f0 = *(const float4*)(ap + kc);
        float4 f1 = *(const float4*)(ap + kc + 4);
        float4 f2 = *(const float4*)(ap + kc + 8);
        float4 f3 = *(const float4*)(ap + kc + 12);
        uint4 b0 = *(const uint4*)(bh_p + kc); uint4 b1 = *(const uint4*)(bh_p + kc + 8);
        uint4 c0 = *(const uint4*)(bl_p + kc); uint4 c1 = *(const uint4*)(bl_p + kc + 8);
        // softmax transform + bf16 hi/lo split in registers
        float vv[16] = {f0.x, f0.y, f0.z, f0.w, f1.x, f1.y, f1.z, f1.w,
                        f2.x, f2.y, f2.z, f2.w, f3.x, f3.y, f3.z, f3.w};
        bf16x8 h0, h1, l0, l1;
#pragma unroll
        for (int e = 0; e < 16; ++e) {
            int col = kc + sseg + e;
            float p = (col <= qrow) ? __expf(vv[e] - mR) * rsR : 0.f;
            __bf16 hi = (__bf16)p;
            __bf16 lo = (__bf16)(p - (float)hi);
            if (e < 8) { h0[e] = hi; l0[e] = lo; }
            else       { h1[e - 8] = hi; l1[e - 8] = lo; }
        }
        __syncthreads();
        *(bf16x8*)&Ah[lbase] = h0; *(bf16x8*)&Ah[lbase + 8] = h1;
        *(bf16x8*)&Al[lbase] = l0; *(bf16x8*)&Al[lbase + 8] = l1;
        *(uint4*)&Bh[lbase] = b0; *(uint4*)&Bh[lbase + 8] = b1;
        *(uint4*)&Bl[lbase] = c0; *(uint4*)&Bl[lbase + 8] = c1;
        __syncthreads();
        bf16x8 fah[4], fal[4], fbh[4], fbl[4];
#pragma unroll
        for (int tm = 0; tm < 4; ++tm) {
            int r = (wy * 64 + tm * 16 + fl) * LSTR + qq * 8;
            fah[tm] = *(const bf16x8*)&Ah[r];
            fal[tm] = *(const bf16x8*)&Al[r];
        }
#pragma unroll
        for (int tn = 0; tn < 4; ++tn) {
            int r = (wx * 64 + tn * 16 + fl) * LSTR + qq * 8;
            fbh[tn] = *(const bf16x8*)&Bh[r];
            fbl[tn] = *(const bf16x8*)&Bl[r];
        }
#pragma unroll
        for (int tm = 0; tm < 4; ++tm)
#pragma unroll
            for (int tn = 0; tn < 4; ++tn) {
                acc[tm][tn] = __builtin_amdgcn_mfma_f32_16x16x32_bf16(fah[tm], fbh[tn], acc[tm][tn], 0, 0, 0);
                acc[tm][tn] = __builtin_amdgcn_mfma_f32_16x16x32_bf16(fah[tm], fbl[tn], acc[tm][tn], 0, 0, 0);
                acc[tm][tn] = __builtin_amdgcn_mfma_f32_16x16x32_bf16(fal[tm], fbh[tn], acc[tm][tn], 0, 0, 0);
            }
    }
    float* Rp = R + (size_t)bh * S_ * 256;
    int grow0 = qt * 128 + wy * 64 + qq * 4;
    int gcol0 = nt * 128 + wx * 64 + fl;
#pragma unroll
    for (int tm = 0; tm < 4; ++tm)
#pragma unroll
        for (int tn = 0; tn < 4; ++tn) {
            size_t base = (size_t)(grow0 + tm * 16) * 256 + gcol0 + tn * 16;
#pragma unroll
            for (int r = 0; r < 4; ++r)
                Rp[base + (size_t)r * 256] = acc[tm][tn][r];
        }
}

// ---------------- fused tail: EMA(FIR-64) + FFN1 + FFN2 + update, 4 rows per block ----------------
#define TROWS 4
__global__ __launch_bounds__(256) void k_tail(const float* __restrict__ R,
                                              const float* __restrict__ apar,
                                              float* __restrict__ x,
                                              const float* __restrict__ iwT, const float* __restrict__ bpT,
                                              const float* __restrict__ acT, const float* __restrict__ asT,
                                              const float* __restrict__ pcT, const float* __restrict__ psT,
                                              const float* __restrict__ wout, const float* __restrict__ bout,
                                              const float* __restrict__ esp, const float* __restrict__ rsp,
                                              __bf16* __restrict__ Xh, __bf16* __restrict__ Xl, int last) {
    int blk = blockIdx.x;            // 512 blocks x 4 rows
    int row0 = blk * TROWS;          // global row = b*S + t
    int b = row0 >> 10, t0 = row0 & 1023;
    int tid = threadIdx.x;
    __shared__ float wsh[2][64];
    __shared__ float emah[TROWS][256];
    __shared__ float xs[TROWS][128];
    __shared__ float csh[TROWS][256], ssh[TROWS][256];
    if (tid < 128) {
        int h = tid >> 6, j = tid & 63;
        float a = 1.f / (1.f + __expf(-apar[h]));
        wsh[h][j] = a * exp2f((float)j * log2f(1.f - a));
    }
    {
        int i0 = tid;
        xs[i0 >> 7][i0 & 127] = x[(size_t)row0 * D_ + i0];
        int i1 = tid + 256;
        xs[i1 >> 7][i1 & 127] = x[(size_t)row0 * D_ + i1];
    }
    __syncthreads();
    // ---- EMA phase: thread = dim (0..255) ----
    {
        int dim = tid;
        if (t0 >= 63) {
#pragma unroll
            for (int r = 0; r < TROWS; ++r) {
                int t = t0 + r;
                float acc = 0.f;
#pragma unroll
                for (int h = 0; h < 2; ++h) {
                    const float* base = R + ((size_t)(b * 2 + h) * S_ + t) * 256 + dim;
                    float s = 0.f;
#pragma unroll
                    for (int j = 0; j < 64; ++j) s = fmaf(wsh[h][j], base[-j * 256], s);
                    acc += s;
                }
                emah[r][dim] = acc;
            }
        } else {
            for (int r = 0; r < TROWS; ++r) {
                int t = t0 + r;
                int jm = t < 63 ? t : 63;
                float acc = 0.f;
                for (int h = 0; h < 2; ++h) {
                    const float* base = R + ((size_t)(b * 2 + h) * S_ + t) * 256 + dim;
                    float s = 0.f;
                    for (int j = 0; j <= jm; ++j) s = fmaf(wsh[h][j], base[-j * 256], s);
                    acc += s;
                }
                emah[r][dim] = acc;
            }
        }
    }
    __syncthreads();
    // ---- FFN1: thread = n (0..255) ----
    {
        int n = tid;
        float ac_[TROWS] = {}, as_[TROWS] = {};
        for (int d = 0; d < 128; ++d) {
            float iw = iwT[d * 256 + n];
            float bp = bpT[d * 256 + n];
            float wc = acT[d * 256 + n];
            float ws2 = asT[d * 256 + n];
#pragma unroll
            for (int r = 0; r < TROWS; ++r) {
                float th = fmaf(xs[r][d], iw, bp);
                float u = fract_(th * INV2PI);
                ac_[r] = fmaf(__builtin_amdgcn_cosf(u), wc, ac_[r]);
                as_[r] = fmaf(__builtin_amdgcn_sinf(u), ws2, as_[r]);
            }
        }
#pragma unroll
        for (int r = 0; r < TROWS; ++r) { csh[r][n] = ac_[r]; ssh[r][n] = as_[r]; }
    }
    __syncthreads();
    // ---- FFN2 + update: g = tid>>7 -> rows {2g, 2g+1}, d = tid&127 ----
    {
        int g = tid >> 7, d = tid & 127;
        float a0 = 0.f, a1 = 0.f;
        for (int nn = 0; nn < 256; ++nn) {
            float pc = pcT[nn * 128 + d], ps = psT[nn * 128 + d];
            a0 = fmaf(csh[g * 2 + 0][nn], pc, fmaf(ssh[g * 2 + 0][nn], ps, a0));
            a1 = fmaf(csh[g * 2 + 1][nn], pc, fmaf(ssh[g * 2 + 1][nn], ps, a1));
        }
        float es = esp[0], rs = rsp[0];
        float wl = 1.f + fabsf(wout[d]);
        float bo = bout[d];
#pragma unroll
        for (int rr = 0; rr < 2; ++rr) {
            int r = g * 2 + rr;
            float v = rr ? a1 : a0;
            float res = v / (1.f + __expf(-v));             // silu
            float comb = emah[r][d] + emah[r][d + 128];
            float th = comb / wl + bo;
            float u = fract_(th * INV2PI);
            float echo = __builtin_amdgcn_cosf(u) + __builtin_amdgcn_sinf(u);
            size_t gi = (size_t)(row0 + r) * D_ + d;
            float xn = xs[r][d] + es * echo + rs * res;
            x[gi] = xn;
            if (last) {
                __bf16 hi = (__bf16)xn;
                Xh[gi] = hi;
                Xl[gi] = (__bf16)(xn - (float)hi);
            }
        }
    }
}

// ---------------- out = X @ P^T via bf16-split MFMA; P split f32->hi/lo on the fly ----------------
__global__ __launch_bounds__(256) void k_out_mfma(const __bf16* __restrict__ Xh, const __bf16* __restrict__ Xl,
                                                  const float* __restrict__ P,
                                                  float* __restrict__ out) {
    __shared__ __bf16 Ah[128 * LSTR], Al[128 * LSTR], Bh[128 * LSTR], Bl[128 * LSTR];
    int mt = blockIdx.x, nt = blockIdx.y;
    int tid = threadIdx.x;
    int wid = tid >> 6, lane = tid & 63;
    int wy = wid >> 1, wx = wid & 1;
    int fl = lane & 15, q = lane >> 4;
    int srow = tid >> 1, sseg = (tid & 1) * 16;
    const __bf16* xh = Xh + (size_t)(mt * 128 + srow) * 128 + sseg;
    const __bf16* xl = Xl + (size_t)(mt * 128 + srow) * 128 + sseg;
    const float* pf = P + (size_t)(nt * 128 + srow) * 128 + sseg;
    int lbase = srow * LSTR + sseg;

    f32x4 acc[4][4];
#pragma unroll
    for (int i = 0; i < 4; ++i)
#pragma unroll
        for (int j = 0; j < 4; ++j) { acc[i][j][0] = 0.f; acc[i][j][1] = 0.f; acc[i][j][2] = 0.f; acc[i][j][3] = 0.f; }

    for (int kc = 0; kc < 128; kc += 32) {
        uint4 vxh0 = *(const uint4*)(xh + kc); uint4 vxh1 = *(const uint4*)(xh + kc + 8);
        uint4 vxl0 = *(const uint4*)(xl + kc); uint4 vxl1 = *(const uint4*)(xl + kc + 8);
        float4 p0 = *(const float4*)(pf + kc);
        float4 p1 = *(const float4*)(pf + kc + 4);
        float4 p2 = *(const float4*)(pf + kc + 8);
        float4 p3 = *(const float4*)(pf + kc + 12);
        float pv_[16] = {p0.x, p0.y, p0.z, p0.w, p1.x, p1.y, p1.z, p1.w,
                         p2.x, p2.y, p2.z, p2.w, p3.x, p3.y, p3.z, p3.w};
        bf16x8 bh0, bh1, bl0, bl1;
#pragma unroll
        for (int e = 0; e < 16; ++e) {
            __bf16 hi = (__bf16)pv_[e];
            __bf16 lo = (__bf16)(pv_[e] - (float)hi);
            if (e < 8) { bh0[e] = hi; bl0[e] = lo; }
            else       { bh1[e - 8] = hi; bl1[e - 8] = lo; }
        }
        __syncthreads();
        *(uint4*)&Ah[lbase] = vxh0; *(uint4*)&Ah[lbase + 8] = vxh1;
        *(uint4*)&Al[lbase] = vxl0; *(uint4*)&Al[lbase + 8] = vxl1;
        *(bf16x8*)&Bh[lbase] = bh0; *(bf16x8*)&Bh[lbase + 8] = bh1;
        *(bf16x8*)&Bl[lbase] = bl0; *(bf16x8*)&Bl[lbase + 8] = bl1;
        __syncthreads();
        bf16x8 ah[4], al[4], bh[4], bl[4];
#pragma unroll
        for (int tm = 0; tm < 4; ++tm) {
            int r = (wy * 64 + tm * 16 + fl) * LSTR + q * 8;
            ah[tm] = *(const bf16x8*)&Ah[r];
            al[tm] = *(const bf16x8*)&Al[r];
        }
#pragma unroll
        for (int tn = 0; tn < 4; ++tn) {
            int r = (wx * 64 + tn * 16 + fl) * LSTR + q * 8;
            bh[tn] = *(const bf16x8*)&Bh[r];
            bl[tn] = *(const bf16x8*)&Bl[r];
        }
#pragma unroll
        for (int tm = 0; tm < 4; ++tm)
#pragma unroll
            for (int tn = 0; tn < 4; ++tn) {
                acc[tm][tn] = __builtin_amdgcn_mfma_f32_16x16x32_bf16(ah[tm], bh[tn], acc[tm][tn], 0, 0, 0);
                acc[tm][tn] = __builtin_amdgcn_mfma_f32_16x16x32_bf16(ah[tm], bl[tn], acc[tm][tn], 0, 0, 0);
                acc[tm][tn] = __builtin_amdgcn_mfma_f32_16x16x32_bf16(al[tm], bh[tn], acc[tm][tn], 0, 0, 0);
            }
    }
    // C/D layout: col = lane&15, row = (lane>>4)*4 + reg  [m89/m91-verified]
    int grow0 = mt * 128 + wy * 64 + q * 4;
    int gcol0 = nt * 128 + wx * 64 + fl;
#pragma unroll
    for (int tm = 0; tm < 4; ++tm)
#pragma unroll
        for (int tn = 0; tn < 4; ++tn) {
            size_t base = (size_t)(grow0 + tm * 16) * V_ + gcol0 + tn * 16;
#pragma unroll
            for (int r = 0; r < 4; ++r)
                out[base + (size_t)r * V_] = acc[tm][tn][r];
        }
}

extern "C" void kernel_launch(void* const* d_in, const int* in_sizes, int n_in,
                              void* d_out, int out_size, void* d_ws, size_t ws_size,
                              hipStream_t stream) {
    const int* ids = (const int*)d_in[0];
    const float* embed = (const float*)d_in[1];
    const float* wq = (const float*)d_in[2];     // (L,H,D)
    const float* bq = (const float*)d_in[3];
    const float* alpha = (const float*)d_in[4];  // (L,H)
    const float* wout = (const float*)d_in[5];   // (L,D)
    const float* bout = (const float*)d_in[6];
    const float* ffnW = (const float*)d_in[7];   // (L,N,D)
    const float* ffnB = (const float*)d_in[8];
    const float* acos_ = (const float*)d_in[9];
    const float* asin_ = (const float*)d_in[10];
    const float* pcos = (const float*)d_in[11];  // (L,D,N)
    const float* psin = (const float*)d_in[12];
    const float* escl = (const float*)d_in[13];  // (L,)
    const float* rscl = (const float*)d_in[14];
    const float* oprj = (const float*)d_in[15];  // (V,D)
    float* out = (float*)d_out;
    float* ws = (float*)d_ws;

    // workspace layout (floats) — footprint identical to the 935us-passing version (10,092,544 floats)
    float* EG = ws;                       // 524288
    float* SR = EG + 524288;              // 262144
    float* SI = SR + 262144;              // 262144
    float* X  = SI + 262144;              // 262144
    float* KB = X + 262144;               // 524288  (KH,KL bf16)
    float* Q0 = KB + 524288;              // 1048576 (QH0,QL0 bf16)
    float* SC = Q0 + 1048576;             // 4194304 (f32 scores; head reused for XH/XL bf16 after last k_pv_sm)
    float* RT = SC + 4194304;             // 1048576
    float* KT = RT + 1048576;             // 524288  (KTH,KTL bf16)
    float* Q1 = KT + 524288;              // 1048576 (QH1,QL1 bf16)
    float* T_IW = Q1 + 1048576;           // 6 x 65536
    float* T_BP = T_IW + 65536;
    float* T_AC = T_BP + 65536;
    float* T_AS = T_AC + 65536;
    float* T_PC = T_AS + 65536;
    float* T_PS = T_PC + 65536;
    // bf16 views
    __bf16* KH = (__bf16*)KB;             // (B,S,256) hi
    __bf16* KL = KH + 524288;             // lo
    __bf16* QH0 = (__bf16*)Q0;            // (B*H,S,256) hi
    __bf16* QL0 = QH0 + 1048576;          // lo
    __bf16* QH1 = (__bf16*)Q1;
    __bf16* QL1 = QH1 + 1048576;
    __bf16* KTH = (__bf16*)KT;            // (B,256,S) hi
    __bf16* KTL = KTH + 524288;           // lo
    // XH/XL overlay the head of SC: SC's last read is layer-1 k_pv_sm, which completes
    // before layer-1 k_tail writes XH/XL (stream-ordered) — race-free overlay.
    __bf16* XH = (__bf16*)SC;             // 262144 bf16
    __bf16* XL = XH + 262144;

    k_gp<<<2304, 256, 0, stream>>>(ids, embed, EG, ffnW, ffnB, acos_, asin_, pcos, psin,
                                   T_IW, T_BP, T_AC, T_AS, T_PC, T_PS);
    k_euler<<<2, 128, 0, stream>>>(EG, SR, SI, X, KH, KL, KTH, KTL);
    k_qq<<<8192, 256, 0, stream>>>(SR, SI, wq, bq, QH0, QL0, QH1, QL1);

    for (int l = 0; l < L_; ++l) {
        k_scores_mfma<<<dim3(8, 8, 4), 256, 0, stream>>>(l ? QH1 : QH0, l ? QL1 : QL0, KH, KL, SC);
        k_pv_sm<<<dim3(2, 8, 4), 256, 0, stream>>>(SC, KTH, KTL, RT);
        k_tail<<<512, 256, 0, stream>>>(RT, alpha + l * H_, X,
                                        T_IW + l * 32768, T_BP + l * 32768,
                                        T_AC + l * 32768, T_AS + l * 32768,
                                        T_PC + l * 32768, T_PS + l * 32768,
                                        wout + l * D_, bout + l * D_,
                                        escl + l, rscl + l, XH, XL, l == L_ - 1);
    }
    k_out_mfma<<<dim3(16, 250), 256, 0, stream>>>(XH, XL, oprj, out);
}

// Round 7
// 831.285 us; speedup vs baseline: 1.1256x; 1.0843x over previous
//
#include <hip/hip_runtime.h>
#include <math.h>

#define B_ 2
#define S_ 1024
#define D_ 128
#define N_ 256
#define L_ 2
#define H_ 2
#define V_ 32000

#define INV2PI 0.15915494309189535f
#define PHI_F 1.61803398874989484f

__device__ __forceinline__ float fract_(float x) { return x - floorf(x); }
// v_sin/v_cos take revolutions; reduce first.
__device__ __forceinline__ float fsin_(float th) { return __builtin_amdgcn_sinf(fract_(th * INV2PI)); }
__device__ __forceinline__ float fcos_(float th) { return __builtin_amdgcn_cosf(fract_(th * INV2PI)); }

typedef __bf16 bf16x8 __attribute__((ext_vector_type(8)));
typedef float f32x4 __attribute__((ext_vector_type(4)));

// ---------------- fused gather (blocks 0..2047) + FFN param prep (blocks 2048..2303) ----------------
__global__ __launch_bounds__(256) void k_gp(const int* __restrict__ ids, const float* __restrict__ embed,
                                            float* __restrict__ eg,
                                            const float* __restrict__ W, const float* __restrict__ Bp,
                                            const float* __restrict__ ac, const float* __restrict__ as2,
                                            const float* __restrict__ pc, const float* __restrict__ ps,
                                            float* __restrict__ iwT, float* __restrict__ bpT,
                                            float* __restrict__ acT, float* __restrict__ asT,
                                            float* __restrict__ pcT, float* __restrict__ psT) {
    int blk = blockIdx.x;
    if (blk < 2048) {
        int i = blk * 256 + threadIdx.x;             // B*S*256
        int c = i & 255, t = (i >> 8) & 1023, b = i >> 18;
        eg[i] = embed[(size_t)ids[b * S_ + t] * 256 + c];
    } else {
        int i = (blk - 2048) * 256 + threadIdx.x;    // L*N*D = 65536
        int d = i & 127, n = (i >> 7) & 255, l = i >> 15;
        int ti = (l * 128 + d) * 256 + n;            // (l,d,n)
        iwT[ti] = 1.f / (1.f + fabsf(W[i]));
        bpT[ti] = Bp[i];
        acT[ti] = ac[i];
        asT[ti] = as2[i];
        // proj_cos is (L,D,N): element (l,d,n) sits at ti -> write (L,N,D)
        pcT[(l * 256 + n) * 128 + d] = pc[ti];
        psT[(l * 256 + n) * 128 + d] = ps[ti];
    }
}

// ---------------- euler scan (minimal): recurrence only, coalesced sr/si stores ----------------
// The 174us of the previous version was store-bound (11 stores/step incl. 2B scatters at 4KB
// stride for K^T). All derived tensors now come from k_fan.
__global__ __launch_bounds__(128) void k_euler(const float* __restrict__ eg,
                                               float* __restrict__ sr, float* __restrict__ si) {
    int b = blockIdx.x;          // 2 blocks
    int d = threadIdx.x;         // 128
    const float* p0 = eg + (size_t)b * S_ * 256 + d;
    float* srp = sr + (size_t)b * S_ * D_ + d;
    float* sip = si + (size_t)b * S_ * D_ + d;
    float h = 0.f;               // h_real + h_imag carry
    double tp = 0.0;             // 2*t*PHI mod 2pi
    const double DTP = 2.0 * 1.6180339887498949;
    const double TWO_PI = 6.283185307179586476925286766559;
    float wA[8], bA[8], wB[8], bB[8];
#pragma unroll
    for (int k = 0; k < 8; ++k) { wA[k] = p0[k * 256]; bA[k] = p0[k * 256 + 128]; }
    for (int g = 0; g < 128; ++g) {
        if (g < 127) {
            const float* p = p0 + (size_t)(g + 1) * 8 * 256;
#pragma unroll
            for (int k = 0; k < 8; ++k) { wB[k] = p[k * 256]; bB[k] = p[k * 256 + 128]; }
        }
#pragma unroll
        for (int k = 0; k < 8; ++k) {
            int t = g * 8 + k;
            float inv = 1.f / (1.f + fabsf(wA[k]));
            float th = fmaf(h, inv, 2.f * bA[k] + (float)tp);
            float u = fract_(th * INV2PI);
            float sn = __builtin_amdgcn_sinf(u);
            float cs = __builtin_amdgcn_cosf(u);
            srp[(size_t)t * D_] = cs;
            sip[(size_t)t * D_] = sn;
            h = cs + sn;
            tp += DTP; if (tp >= TWO_PI) tp -= TWO_PI;
        }
#pragma unroll
        for (int k = 0; k < 8; ++k) { wA[k] = wB[k]; bA[k] = bB[k]; }
    }
}

// ---------------- fan-out: sr/si -> x, K row-major bf16 hi/lo, K^T bf16 hi/lo (LDS transpose) ----
__global__ __launch_bounds__(256) void k_fan(const float* __restrict__ sr, const float* __restrict__ si,
                                             float* __restrict__ x,
                                             __bf16* __restrict__ Kh, __bf16* __restrict__ Kl,
                                             __bf16* __restrict__ KTh, __bf16* __restrict__ KTl) {
    __shared__ float tc[32][33], ts[32][33];
    int b = blockIdx.z;
    int t0 = blockIdx.x * 32, d0 = blockIdx.y * 32;    // d0 in {0,32,64,96}
    int lx = threadIdx.x & 31, ly = threadIdx.x >> 5;  // 32 x 8
#pragma unroll
    for (int i = 0; i < 4; ++i) {
        int tr = ly + i * 8;
        int t = t0 + tr;
        size_t si_ = ((size_t)b * S_ + t) * D_ + d0 + lx;
        float cs = sr[si_];
        float sn = si[si_];
        tc[tr][lx] = cs; ts[tr][lx] = sn;
        x[si_] = cs + sn;
        __bf16 ch = (__bf16)cs; __bf16 cl = (__bf16)(cs - (float)ch);
        __bf16 sh2 = (__bf16)sn; __bf16 sl = (__bf16)(sn - (float)sh2);
        size_t ki = ((size_t)b * S_ + t) * 256 + d0 + lx;
        Kh[ki] = ch; Kl[ki] = cl;
        Kh[ki + 128] = sh2; Kl[ki + 128] = sl;
    }
    __syncthreads();
#pragma unroll
    for (int i = 0; i < 4; ++i) {
        int dr = ly + i * 8;
        int d = d0 + dr;
        float cs = tc[lx][dr], sn = ts[lx][dr];
        __bf16 ch = (__bf16)cs; __bf16 cl = (__bf16)(cs - (float)ch);
        __bf16 sh2 = (__bf16)sn; __bf16 sl = (__bf16)(sn - (float)sh2);
        size_t k1 = ((size_t)b * 256 + d) * S_ + t0 + lx;
        size_t k2 = ((size_t)b * 256 + d + 128) * S_ + t0 + lx;
        KTh[k1] = ch; KTl[k1] = cl;
        KTh[k2] = sh2; KTl[k2] = sl;
    }
}

// ---------------- Q for BOTH layers: bf16 hi/lo, layout (l)(B,H,S,2D) ----------------
__global__ __launch_bounds__(256) void k_qq(const float* __restrict__ sr, const float* __restrict__ si,
                                            const float* __restrict__ wq, const float* __restrict__ bq,
                                            __bf16* __restrict__ Qh0, __bf16* __restrict__ Ql0,
                                            __bf16* __restrict__ Qh1, __bf16* __restrict__ Ql1) {
    int i = blockIdx.x * 256 + threadIdx.x;      // 2 * 2^20
    int l = i >> 20;
    int j = i & 0xFFFFF;
    int c = j & 255;
    int s = (j >> 8) & 1023;
    int bh = j >> 18;           // b*H + h
    int h = bh & 1, b = bh >> 1;
    int d = c & 127;
    const float* st = (c < 128) ? sr : si;
    float v = st[((size_t)b * S_ + s) * D_ + d];
    float w = wq[(l * H_ + h) * D_ + d], bb = bq[(l * H_ + h) * D_ + d];
    float th = v / (1.f + fabsf(w)) + bb + (float)s * PHI_F;
    float qv = fcos_(th);
    __bf16 hq = (__bf16)qv;
    __bf16 lq = (__bf16)(qv - (float)hq);
    if (l == 0) { Qh0[j] = hq; Ql0[j] = lq; }
    else        { Qh1[j] = hq; Ql1[j] = lq; }
}

#define LSTR 40   // 32 k + 8 pad (bf16 elems): row stride 80 B, 16B-aligned, ~2-way banks

// ---------------- scores = Q K^T / 16 via bf16-split MFMA (hh + hl + lh), f32 out ----------------
__global__ __launch_bounds__(256) void k_scores_mfma(const __bf16* __restrict__ Qh, const __bf16* __restrict__ Ql,
                                                     const __bf16* __restrict__ Kh, const __bf16* __restrict__ Kl,
                                                     float* __restrict__ sc) {
    int kt = blockIdx.x, qt = blockIdx.y, bh = blockIdx.z;
    if (kt > qt) return;
    __shared__ __bf16 Ah[128 * LSTR], Al[128 * LSTR], Bh[128 * LSTR], Bl[128 * LSTR];
    int tid = threadIdx.x;
    int wid = tid >> 6, lane = tid & 63;
    int wy = wid >> 1, wx = wid & 1;
    int fl = lane & 15, qq = lane >> 4;
    int srow = tid >> 1, sseg = (tid & 1) * 16;
    const __bf16* qh = Qh + ((size_t)bh * S_ + qt * 128 + srow) * 256 + sseg;
    const __bf16* ql = Ql + ((size_t)bh * S_ + qt * 128 + srow) * 256 + sseg;
    const __bf16* kh = Kh + ((size_t)(bh >> 1) * S_ + kt * 128 + srow) * 256 + sseg;
    const __bf16* kl = Kl + ((size_t)(bh >> 1) * S_ + kt * 128 + srow) * 256 + sseg;
    int lbase = srow * LSTR + sseg;

    f32x4 acc[4][4];
#pragma unroll
    for (int i = 0; i < 4; ++i)
#pragma unroll
        for (int j = 0; j < 4; ++j) { acc[i][j][0] = 0.f; acc[i][j][1] = 0.f; acc[i][j][2] = 0.f; acc[i][j][3] = 0.f; }

    for (int kc = 0; kc < 256; kc += 32) {
        uint4 a0 = *(const uint4*)(qh + kc); uint4 a1 = *(const uint4*)(qh + kc + 8);
        uint4 l0 = *(const uint4*)(ql + kc); uint4 l1 = *(const uint4*)(ql + kc + 8);
        uint4 b0 = *(const uint4*)(kh + kc); uint4 b1 = *(const uint4*)(kh + kc + 8);
        uint4 c0 = *(const uint4*)(kl + kc); uint4 c1 = *(const uint4*)(kl + kc + 8);
        __syncthreads();
        *(uint4*)&Ah[lbase] = a0; *(uint4*)&Ah[lbase + 8] = a1;
        *(uint4*)&Al[lbase] = l0; *(uint4*)&Al[lbase + 8] = l1;
        *(uint4*)&Bh[lbase] = b0; *(uint4*)&Bh[lbase + 8] = b1;
        *(uint4*)&Bl[lbase] = c0; *(uint4*)&Bl[lbase + 8] = c1;
        __syncthreads();
        bf16x8 fah[4], fal[4], fbh[4], fbl[4];
#pragma unroll
        for (int tm = 0; tm < 4; ++tm) {
            int r = (wy * 64 + tm * 16 + fl) * LSTR + qq * 8;
            fah[tm] = *(const bf16x8*)&Ah[r];
            fal[tm] = *(const bf16x8*)&Al[r];
        }
#pragma unroll
        for (int tn = 0; tn < 4; ++tn) {
            int r = (wx * 64 + tn * 16 + fl) * LSTR + qq * 8;
            fbh[tn] = *(const bf16x8*)&Bh[r];
            fbl[tn] = *(const bf16x8*)&Bl[r];
        }
#pragma unroll
        for (int tm = 0; tm < 4; ++tm)
#pragma unroll
            for (int tn = 0; tn < 4; ++tn) {
                acc[tm][tn] = __builtin_amdgcn_mfma_f32_16x16x32_bf16(fah[tm], fbh[tn], acc[tm][tn], 0, 0, 0);
                acc[tm][tn] = __builtin_amdgcn_mfma_f32_16x16x32_bf16(fah[tm], fbl[tn], acc[tm][tn], 0, 0, 0);
                acc[tm][tn] = __builtin_amdgcn_mfma_f32_16x16x32_bf16(fal[tm], fbh[tn], acc[tm][tn], 0, 0, 0);
            }
    }
    // C/D layout: col = lane&15, row = (lane>>4)*4 + reg  [m89/m91-verified]
    const float s16 = 0.0625f;
    float* Cp = sc + (size_t)bh * S_ * S_;
    int grow0 = qt * 128 + wy * 64 + qq * 4;
    int gcol0 = kt * 128 + wx * 64 + fl;
#pragma unroll
    for (int tm = 0; tm < 4; ++tm)
#pragma unroll
        for (int tn = 0; tn < 4; ++tn) {
            size_t base = (size_t)(grow0 + tm * 16) * S_ + gcol0 + tn * 16;
#pragma unroll
            for (int r = 0; r < 4; ++r)
                Cp[base + (size_t)r * S_] = acc[tm][tn][r] * s16;
        }
}

// ---------------- fused softmax + PV: row stats (2 thr/row) then exp-transform in A-staging -------
__global__ __launch_bounds__(256) void k_pv_sm(const float* __restrict__ SCf,
                                               const __bf16* __restrict__ KTh, const __bf16* __restrict__ KTl,
                                               float* __restrict__ R) {
    __shared__ __bf16 Ah[128 * LSTR], Al[128 * LSTR], Bh[128 * LSTR], Bl[128 * LSTR];
    __shared__ float mrow[128], rrow[128];
    int nt = blockIdx.x, qt = blockIdx.y, bh = blockIdx.z;
    int tid = threadIdx.x;
    int wid = tid >> 6, lane = tid & 63;
    int wy = wid >> 1, wx = wid & 1;
    int fl = lane & 15, qq = lane >> 4;
    int srow = tid >> 1, half = tid & 1, sseg = half * 16;
    const float* Sp = SCf + (size_t)bh * S_ * S_;
    int kceil = qt * 128 + 128;
    // ---- row stats: max then sum (masked at causal boundary) ----
    {
        int r = srow;
        int q = qt * 128 + r;
        const float* rp = Sp + (size_t)q * S_;
        float m = -3e38f;
        for (int c = half * 4; c < kceil; c += 8) {
            float4 v = *(const float4*)&rp[c];
            if (c + 0 <= q) m = fmaxf(m, v.x);
            if (c + 1 <= q) m = fmaxf(m, v.y);
            if (c + 2 <= q) m = fmaxf(m, v.z);
            if (c + 3 <= q) m = fmaxf(m, v.w);
        }
        m = fmaxf(m, __shfl_xor(m, 1));
        float s = 0.f;
        for (int c = half * 4; c < kceil; c += 8) {
            float4 v = *(const float4*)&rp[c];
            if (c + 0 <= q) s += __expf(v.x - m);
            if (c + 1 <= q) s += __expf(v.y - m);
            if (c + 2 <= q) s += __expf(v.z - m);
            if (c + 3 <= q) s += __expf(v.w - m);
        }
        s += __shfl_xor(s, 1);
        mrow[r] = m;
        rrow[r] = 1.f / s;
    }
    __syncthreads();
    float mR = mrow[srow], rsR = rrow[srow];
    int qrow = qt * 128 + srow;
    const float* ap = Sp + (size_t)qrow * S_ + sseg;
    const __bf16* bh_p = KTh + ((size_t)(bh >> 1) * 256 + nt * 128 + srow) * S_ + sseg;
    const __bf16* bl_p = KTl + ((size_t)(bh >> 1) * 256 + nt * 128 + srow) * S_ + sseg;
    int lbase = srow * LSTR + sseg;

    f32x4 acc[4][4];
#pragma unroll
    for (int i = 0; i < 4; ++i)
#pragma unroll
        for (int j = 0; j < 4; ++j) { acc[i][j][0] = 0.f; acc[i][j][1] = 0.f; acc[i][j][2] = 0.f; acc[i][j][3] = 0.f; }

    for (int kc = 0; kc < kceil; kc += 32) {
        float4 f0 = *(const float4*)(ap + kc);
        float4 f1 = *(const float4*)(ap + kc + 4);
        float4 f2 = *(const float4*)(ap + kc + 8);
        float4 f3 = *(const float4*)(ap + kc + 12);
        uint4 b0 = *(const uint4*)(bh_p + kc); uint4 b1 = *(const uint4*)(bh_p + kc + 8);
        uint4 c0 = *(const uint4*)(bl_p + kc); uint4 c1 = *(const uint4*)(bl_p + kc + 8);
        // softmax transform + bf16 hi/lo split in registers
        float vv[16] = {f0.x, f0.y, f0.z, f0.w, f1.x, f1.y, f1.z, f1.w,
                        f2.x, f2.y, f2.z, f2.w, f3.x, f3.y, f3.z, f3.w};
        bf16x8 h0, h1, l0, l1;
#pragma unroll
        for (int e = 0; e < 16; ++e) {
            int col = kc + sseg + e;
            float p = (col <= qrow) ? __expf(vv[e] - mR) * rsR : 0.f;
            __bf16 hi = (__bf16)p;
            __bf16 lo = (__bf16)(p - (float)hi);
            if (e < 8) { h0[e] = hi; l0[e] = lo; }
            else       { h1[e - 8] = hi; l1[e - 8] = lo; }
        }
        __syncthreads();
        *(bf16x8*)&Ah[lbase] = h0; *(bf16x8*)&Ah[lbase + 8] = h1;
        *(bf16x8*)&Al[lbase] = l0; *(bf16x8*)&Al[lbase + 8] = l1;
        *(uint4*)&Bh[lbase] = b0; *(uint4*)&Bh[lbase + 8] = b1;
        *(uint4*)&Bl[lbase] = c0; *(uint4*)&Bl[lbase + 8] = c1;
        __syncthreads();
        bf16x8 fah[4], fal[4], fbh[4], fbl[4];
#pragma unroll
        for (int tm = 0; tm < 4; ++tm) {
            int r = (wy * 64 + tm * 16 + fl) * LSTR + qq * 8;
            fah[tm] = *(const bf16x8*)&Ah[r];
            fal[tm] = *(const bf16x8*)&Al[r];
        }
#pragma unroll
        for (int tn = 0; tn < 4; ++tn) {
            int r = (wx * 64 + tn * 16 + fl) * LSTR + qq * 8;
            fbh[tn] = *(const bf16x8*)&Bh[r];
            fbl[tn] = *(const bf16x8*)&Bl[r];
        }
#pragma unroll
        for (int tm = 0; tm < 4; ++tm)
#pragma unroll
            for (int tn = 0; tn < 4; ++tn) {
                acc[tm][tn] = __builtin_amdgcn_mfma_f32_16x16x32_bf16(fah[tm], fbh[tn], acc[tm][tn], 0, 0, 0);
                acc[tm][tn] = __builtin_amdgcn_mfma_f32_16x16x32_bf16(fah[tm], fbl[tn], acc[tm][tn], 0, 0, 0);
                acc[tm][tn] = __builtin_amdgcn_mfma_f32_16x16x32_bf16(fal[tm], fbh[tn], acc[tm][tn], 0, 0, 0);
            }
    }
    float* Rp = R + (size_t)bh * S_ * 256;
    int grow0 = qt * 128 + wy * 64 + qq * 4;
    int gcol0 = nt * 128 + wx * 64 + fl;
#pragma unroll
    for (int tm = 0; tm < 4; ++tm)
#pragma unroll
        for (int tn = 0; tn < 4; ++tn) {
            size_t base = (size_t)(grow0 + tm * 16) * 256 + gcol0 + tn * 16;
#pragma unroll
            for (int r = 0; r < 4; ++r)
                Rp[base + (size_t)r * 256] = acc[tm][tn][r];
        }
}

// ---------------- fused tail: EMA(FIR-64) + FFN1 + FFN2 + update, 4 rows per block ----------------
#define TROWS 4
__global__ __launch_bounds__(256) void k_tail(const float* __restrict__ R,
                                              const float* __restrict__ apar,
                                              float* __restrict__ x,
                                              const float* __restrict__ iwT, const float* __restrict__ bpT,
                                              const float* __restrict__ acT, const float* __restrict__ asT,
                                              const float* __restrict__ pcT, const float* __restrict__ psT,
                                              const float* __restrict__ wout, const float* __restrict__ bout,
                                              const float* __restrict__ esp, const float* __restrict__ rsp,
                                              __bf16* __restrict__ Xh, __bf16* __restrict__ Xl, int last) {
    int blk = blockIdx.x;            // 512 blocks x 4 rows
    int row0 = blk * TROWS;          // global row = b*S + t
    int b = row0 >> 10, t0 = row0 & 1023;
    int tid = threadIdx.x;
    __shared__ float wsh[2][64];
    __shared__ float emah[TROWS][256];
    __shared__ float xs[TROWS][128];
    __shared__ float csh[TROWS][256], ssh[TROWS][256];
    if (tid < 128) {
        int h = tid >> 6, j = tid & 63;
        float a = 1.f / (1.f + __expf(-apar[h]));
        wsh[h][j] = a * exp2f((float)j * log2f(1.f - a));
    }
    {
        int i0 = tid;
        xs[i0 >> 7][i0 & 127] = x[(size_t)row0 * D_ + i0];
        int i1 = tid + 256;
        xs[i1 >> 7][i1 & 127] = x[(size_t)row0 * D_ + i1];
    }
    __syncthreads();
    // ---- EMA phase: thread = dim (0..255) ----
    {
        int dim = tid;
        if (t0 >= 63) {
#pragma unroll
            for (int r = 0; r < TROWS; ++r) {
                int t = t0 + r;
                float acc = 0.f;
#pragma unroll
                for (int h = 0; h < 2; ++h) {
                    const float* base = R + ((size_t)(b * 2 + h) * S_ + t) * 256 + dim;
                    float s = 0.f;
#pragma unroll
                    for (int j = 0; j < 64; ++j) s = fmaf(wsh[h][j], base[-j * 256], s);
                    acc += s;
                }
                emah[r][dim] = acc;
            }
        } else {
            for (int r = 0; r < TROWS; ++r) {
                int t = t0 + r;
                int jm = t < 63 ? t : 63;
                float acc = 0.f;
                for (int h = 0; h < 2; ++h) {
                    const float* base = R + ((size_t)(b * 2 + h) * S_ + t) * 256 + dim;
                    float s = 0.f;
                    for (int j = 0; j <= jm; ++j) s = fmaf(wsh[h][j], base[-j * 256], s);
                    acc += s;
                }
                emah[r][dim] = acc;
            }
        }
    }
    __syncthreads();
    // ---- FFN1: thread = n (0..255) ----
    {
        int n = tid;
        float ac_[TROWS] = {}, as_[TROWS] = {};
        for (int d = 0; d < 128; ++d) {
            float iw = iwT[d * 256 + n];
            float bp = bpT[d * 256 + n];
            float wc = acT[d * 256 + n];
            float ws2 = asT[d * 256 + n];
#pragma unroll
            for (int r = 0; r < TROWS; ++r) {
                float th = fmaf(xs[r][d], iw, bp);
                float u = fract_(th * INV2PI);
                ac_[r] = fmaf(__builtin_amdgcn_cosf(u), wc, ac_[r]);
                as_[r] = fmaf(__builtin_amdgcn_sinf(u), ws2, as_[r]);
            }
        }
#pragma unroll
        for (int r = 0; r < TROWS; ++r) { csh[r][n] = ac_[r]; ssh[r][n] = as_[r]; }
    }
    __syncthreads();
    // ---- FFN2 + update: g = tid>>7 -> rows {2g, 2g+1}, d = tid&127 ----
    {
        int g = tid >> 7, d = tid & 127;
        float a0 = 0.f, a1 = 0.f;
        for (int nn = 0; nn < 256; ++nn) {
            float pc = pcT[nn * 128 + d], ps = psT[nn * 128 + d];
            a0 = fmaf(csh[g * 2 + 0][nn], pc, fmaf(ssh[g * 2 + 0][nn], ps, a0));
            a1 = fmaf(csh[g * 2 + 1][nn], pc, fmaf(ssh[g * 2 + 1][nn], ps, a1));
        }
        float es = esp[0], rs = rsp[0];
        float wl = 1.f + fabsf(wout[d]);
        float bo = bout[d];
#pragma unroll
        for (int rr = 0; rr < 2; ++rr) {
            int r = g * 2 + rr;
            float v = rr ? a1 : a0;
            float res = v / (1.f + __expf(-v));             // silu
            float comb = emah[r][d] + emah[r][d + 128];
            float th = comb / wl + bo;
            float u = fract_(th * INV2PI);
            float echo = __builtin_amdgcn_cosf(u) + __builtin_amdgcn_sinf(u);
            size_t gi = (size_t)(row0 + r) * D_ + d;
            float xn = xs[r][d] + es * echo + rs * res;
            x[gi] = xn;
            if (last) {
                __bf16 hi = (__bf16)xn;
                Xh[gi] = hi;
                Xl[gi] = (__bf16)(xn - (float)hi);
            }
        }
    }
}

// ---------------- out = X @ P^T via bf16-split MFMA; P split f32->hi/lo on the fly ----------------
__global__ __launch_bounds__(256) void k_out_mfma(const __bf16* __restrict__ Xh, const __bf16* __restrict__ Xl,
                                                  const float* __restrict__ P,
                                                  float* __restrict__ out) {
    __shared__ __bf16 Ah[128 * LSTR], Al[128 * LSTR], Bh[128 * LSTR], Bl[128 * LSTR];
    int mt = blockIdx.x, nt = blockIdx.y;
    int tid = threadIdx.x;
    int wid = tid >> 6, lane = tid & 63;
    int wy = wid >> 1, wx = wid & 1;
    int fl = lane & 15, q = lane >> 4;
    int srow = tid >> 1, sseg = (tid & 1) * 16;
    const __bf16* xh = Xh + (size_t)(mt * 128 + srow) * 128 + sseg;
    const __bf16* xl = Xl + (size_t)(mt * 128 + srow) * 128 + sseg;
    const float* pf = P + (size_t)(nt * 128 + srow) * 128 + sseg;
    int lbase = srow * LSTR + sseg;

    f32x4 acc[4][4];
#pragma unroll
    for (int i = 0; i < 4; ++i)
#pragma unroll
        for (int j = 0; j < 4; ++j) { acc[i][j][0] = 0.f; acc[i][j][1] = 0.f; acc[i][j][2] = 0.f; acc[i][j][3] = 0.f; }

    for (int kc = 0; kc < 128; kc += 32) {
        uint4 vxh0 = *(const uint4*)(xh + kc); uint4 vxh1 = *(const uint4*)(xh + kc + 8);
        uint4 vxl0 = *(const uint4*)(xl + kc); uint4 vxl1 = *(const uint4*)(xl + kc + 8);
        float4 p0 = *(const float4*)(pf + kc);
        float4 p1 = *(const float4*)(pf + kc + 4);
        float4 p2 = *(const float4*)(pf + kc + 8);
        float4 p3 = *(const float4*)(pf + kc + 12);
        float pv_[16] = {p0.x, p0.y, p0.z, p0.w, p1.x, p1.y, p1.z, p1.w,
                         p2.x, p2.y, p2.z, p2.w, p3.x, p3.y, p3.z, p3.w};
        bf16x8 bh0, bh1, bl0, bl1;
#pragma unroll
        for (int e = 0; e < 16; ++e) {
            __bf16 hi = (__bf16)pv_[e];
            __bf16 lo = (__bf16)(pv_[e] - (float)hi);
            if (e < 8) { bh0[e] = hi; bl0[e] = lo; }
            else       { bh1[e - 8] = hi; bl1[e - 8] = lo; }
        }
        __syncthreads();
        *(uint4*)&Ah[lbase] = vxh0; *(uint4*)&Ah[lbase + 8] = vxh1;
        *(uint4*)&Al[lbase] = vxl0; *(uint4*)&Al[lbase + 8] = vxl1;
        *(bf16x8*)&Bh[lbase] = bh0; *(bf16x8*)&Bh[lbase + 8] = bh1;
        *(bf16x8*)&Bl[lbase] = bl0; *(bf16x8*)&Bl[lbase + 8] = bl1;
        __syncthreads();
        bf16x8 ah[4], al[4], bh[4], bl[4];
#pragma unroll
        for (int tm = 0; tm < 4; ++tm) {
            int r = (wy * 64 + tm * 16 + fl) * LSTR + q * 8;
            ah[tm] = *(const bf16x8*)&Ah[r];
            al[tm] = *(const bf16x8*)&Al[r];
        }
#pragma unroll
        for (int tn = 0; tn < 4; ++tn) {
            int r = (wx * 64 + tn * 16 + fl) * LSTR + q * 8;
            bh[tn] = *(const bf16x8*)&Bh[r];
            bl[tn] = *(const bf16x8*)&Bl[r];
        }
#pragma unroll
        for (int tm = 0; tm < 4; ++tm)
#pragma unroll
            for (int tn = 0; tn < 4; ++tn) {
                acc[tm][tn] = __builtin_amdgcn_mfma_f32_16x16x32_bf16(ah[tm], bh[tn], acc[tm][tn], 0, 0, 0);
                acc[tm][tn] = __builtin_amdgcn_mfma_f32_16x16x32_bf16(ah[tm], bl[tn], acc[tm][tn], 0, 0, 0);
                acc[tm][tn] = __builtin_amdgcn_mfma_f32_16x16x32_bf16(al[tm], bh[tn], acc[tm][tn], 0, 0, 0);
            }
    }
    // C/D layout: col = lane&15, row = (lane>>4)*4 + reg  [m89/m91-verified]
    int grow0 = mt * 128 + wy * 64 + q * 4;
    int gcol0 = nt * 128 + wx * 64 + fl;
#pragma unroll
    for (int tm = 0; tm < 4; ++tm)
#pragma unroll
        for (int tn = 0; tn < 4; ++tn) {
            size_t base = (size_t)(grow0 + tm * 16) * V_ + gcol0 + tn * 16;
#pragma unroll
            for (int r = 0; r < 4; ++r)
                out[base + (size_t)r * V_] = acc[tm][tn][r];
        }
}

extern "C" void kernel_launch(void* const* d_in, const int* in_sizes, int n_in,
                              void* d_out, int out_size, void* d_ws, size_t ws_size,
                              hipStream_t stream) {
    const int* ids = (const int*)d_in[0];
    const float* embed = (const float*)d_in[1];
    const float* wq = (const float*)d_in[2];     // (L,H,D)
    const float* bq = (const float*)d_in[3];
    const float* alpha = (const float*)d_in[4];  // (L,H)
    const float* wout = (const float*)d_in[5];   // (L,D)
    const float* bout = (const float*)d_in[6];
    const float* ffnW = (const float*)d_in[7];   // (L,N,D)
    const float* ffnB = (const float*)d_in[8];
    const float* acos_ = (const float*)d_in[9];
    const float* asin_ = (const float*)d_in[10];
    const float* pcos = (const float*)d_in[11];  // (L,D,N)
    const float* psin = (const float*)d_in[12];
    const float* escl = (const float*)d_in[13];  // (L,)
    const float* rscl = (const float*)d_in[14];
    const float* oprj = (const float*)d_in[15];  // (V,D)
    float* out = (float*)d_out;
    float* ws = (float*)d_ws;

    // workspace layout (floats) — footprint identical to the 935us-passing version (10,092,544 floats)
    float* EG = ws;                       // 524288
    float* SR = EG + 524288;              // 262144
    float* SI = SR + 262144;              // 262144
    float* X  = SI + 262144;              // 262144
    float* KB = X + 262144;               // 524288  (KH,KL bf16)
    float* Q0 = KB + 524288;              // 1048576 (QH0,QL0 bf16)
    float* SC = Q0 + 1048576;             // 4194304 (f32 scores; head reused for XH/XL bf16 after last k_pv_sm)
    float* RT = SC + 4194304;             // 1048576
    float* KT = RT + 1048576;             // 524288  (KTH,KTL bf16)
    float* Q1 = KT + 524288;              // 1048576 (QH1,QL1 bf16)
    float* T_IW = Q1 + 1048576;           // 6 x 65536
    float* T_BP = T_IW + 65536;
    float* T_AC = T_BP + 65536;
    float* T_AS = T_AC + 65536;
    float* T_PC = T_AS + 65536;
    float* T_PS = T_PC + 65536;
    // bf16 views
    __bf16* KH = (__bf16*)KB;             // (B,S,256) hi
    __bf16* KL = KH + 524288;             // lo
    __bf16* QH0 = (__bf16*)Q0;            // (B*H,S,256) hi
    __bf16* QL0 = QH0 + 1048576;          // lo
    __bf16* QH1 = (__bf16*)Q1;
    __bf16* QL1 = QH1 + 1048576;
    __bf16* KTH = (__bf16*)KT;            // (B,256,S) hi
    __bf16* KTL = KTH + 524288;           // lo
    // XH/XL overlay the head of SC: SC's last read is layer-1 k_pv_sm, which completes
    // before layer-1 k_tail writes XH/XL (stream-ordered) — race-free overlay.
    __bf16* XH = (__bf16*)SC;             // 262144 bf16
    __bf16* XL = XH + 262144;

    k_gp<<<2304, 256, 0, stream>>>(ids, embed, EG, ffnW, ffnB, acos_, asin_, pcos, psin,
                                   T_IW, T_BP, T_AC, T_AS, T_PC, T_PS);
    k_euler<<<2, 128, 0, stream>>>(EG, SR, SI);
    k_fan<<<dim3(32, 4, 2), 256, 0, stream>>>(SR, SI, X, KH, KL, KTH, KTL);
    k_qq<<<8192, 256, 0, stream>>>(SR, SI, wq, bq, QH0, QL0, QH1, QL1);

    for (int l = 0; l < L_; ++l) {
        k_scores_mfma<<<dim3(8, 8, 4), 256, 0, stream>>>(l ? QH1 : QH0, l ? QL1 : QL0, KH, KL, SC);
        k_pv_sm<<<dim3(2, 8, 4), 256, 0, stream>>>(SC, KTH, KTL, RT);
        k_tail<<<512, 256, 0, stream>>>(RT, alpha + l * H_, X,
                                        T_IW + l * 32768, T_BP + l * 32768,
                                        T_AC + l * 32768, T_AS + l * 32768,
                                        T_PC + l * 32768, T_PS + l * 32768,
                                        wout + l * D_, bout + l * D_,
                                        escl + l, rscl + l, XH, XL, l == L_ - 1);
    }
    k_out_mfma<<<dim3(16, 250), 256, 0, stream>>>(XH, XL, oprj, out);
}